// Round 9
// baseline (580.074 us; speedup 1.0000x reference)
//
#include <hip/hip_runtime.h>
#include <cstdint>
#include <cstddef>

#define NEG_SLOPE 0.2f
#define BN_EPS 1e-5f

typedef __bf16 bf16x8 __attribute__((ext_vector_type(8)));
typedef float  f32x4  __attribute__((ext_vector_type(4)));

// ---------- prep: x fp32 [N][K] -> bf16 [N][Kpad] zero-padded ----------
__global__ void conv_pad_kernel(const float* __restrict__ x, __bf16* __restrict__ xb,
                                int N, int K, int Kpad) {
    int i = blockIdx.x * blockDim.x + threadIdx.x;
    int total = N * Kpad;
    for (; i < total; i += gridDim.x * blockDim.x) {
        int n = i / Kpad, k = i - n * Kpad;
        xb[i] = (k < K) ? (__bf16)x[(size_t)n * K + k] : (__bf16)0.f;
    }
}

// ---------- prep: all 4 weight transposes in one launch ----------
__global__ void wtrans_all_kernel(const float* __restrict__ W1, const float* __restrict__ W2,
                                  const float* __restrict__ W3, const float* __restrict__ W4,
                                  __bf16* __restrict__ wt1, __bf16* __restrict__ wt2,
                                  __bf16* __restrict__ wt3, __bf16* __restrict__ wt4, int IN) {
    int b = blockIdx.x;
    const float* W; __bf16* WT; int K, D, Kpad, col;
    if (b < 256)      { W = W1; WT = wt1; K = IN;  D = 256; Kpad = 64;  col = b; }
    else if (b < 512) { W = W2; WT = wt2; K = 256; D = 256; Kpad = 256; col = b - 256; }
    else if (b < 768) { W = W3; WT = wt3; K = 256; D = 256; Kpad = 256; col = b - 512; }
    else              { W = W4; WT = wt4; K = 256; D = 128; Kpad = 256; col = b - 768; }
    for (int k = threadIdx.x; k < Kpad; k += blockDim.x)
        WT[(size_t)col * Kpad + k] = (k < K) ? (__bf16)W[(size_t)k * D + col] : (__bf16)0.f;
}

// ================= LDS-free MFMA GEMM strip + fused alpha =================
template<int DCOLS, int HEADS, bool HAS_A2>
__global__ __launch_bounds__(256) void gemm_fused(
    const __bf16* __restrict__ A, const __bf16* __restrict__ A2,
    const __bf16* __restrict__ WT,
    const float* __restrict__ asv, const float* __restrict__ adv,
    __bf16* __restrict__ H, float* __restrict__ alpha_s, float* __restrict__ alpha_d,
    int M, int K) {
    constexpr int RB = (DCOLS == 256) ? 64 : 128;
    const int w    = threadIdx.x >> 6;
    const int lane = threadIdx.x & 63;
    const int l16  = lane & 15, hi4 = lane >> 4;
    const int rg    = (DCOLS == 256) ? 0 : (w >> 1);
    const int ct    = (DCOLS == 256) ? w : (w & 1);
    const int col0w = ct * 64;
    const int rbase = rg * 64;
    const int n0 = blockIdx.x * RB;
    const int lk = hi4 * 8;

    f32x4 acc[4][4] = {};
    int arow[4];
    #pragma unroll
    for (int i = 0; i < 4; ++i) {
        int r = n0 + rbase + i * 16 + l16;
        arow[i] = (r < M) ? r : (M - 1);
    }

    for (int k0 = 0; k0 < K; k0 += 32) {
        bf16x8 af[4], bfr[4];
        #pragma unroll
        for (int i = 0; i < 4; ++i) {
            bf16x8 v = *(const bf16x8*)&A[(size_t)arow[i] * K + k0 + lk];
            if (HAS_A2) {
                bf16x8 v2 = *(const bf16x8*)&A2[(size_t)arow[i] * K + k0 + lk];
                #pragma unroll
                for (int j = 0; j < 8; ++j) v[j] = (__bf16)((float)v[j] + (float)v2[j]);
            }
            af[i] = v;
        }
        #pragma unroll
        for (int j = 0; j < 4; ++j)
            bfr[j] = *(const bf16x8*)&WT[(size_t)(col0w + j * 16 + l16) * K + k0 + lk];
        #pragma unroll
        for (int i = 0; i < 4; ++i)
            #pragma unroll
            for (int j = 0; j < 4; ++j)
                acc[i][j] = __builtin_amdgcn_mfma_f32_16x16x32_bf16(
                    af[i], bfr[j], acc[i][j], 0, 0, 0);
    }

    #pragma unroll
    for (int i = 0; i < 4; ++i)
        #pragma unroll
        for (int q = 0; q < 4; ++q) {
            int row = n0 + rbase + i * 16 + hi4 * 4 + q;
            if (row < M)
                #pragma unroll
                for (int j = 0; j < 4; ++j)
                    H[(size_t)row * DCOLS + col0w + j * 16 + l16] = (__bf16)acc[i][j][q];
        }

    float asc[4], adc[4];
    #pragma unroll
    for (int j = 0; j < 4; ++j) {
        int c = col0w + j * 16 + l16;
        asc[j] = asv[c]; adc[j] = adv[c];
    }
    __shared__ float as_l[128][2], ad_l[128][2];
    #pragma unroll
    for (int i = 0; i < 4; ++i)
        #pragma unroll
        for (int q = 0; q < 4; ++q) {
            float ps = 0.f, pd = 0.f;
            #pragma unroll
            for (int j = 0; j < 4; ++j) {
                float v = acc[i][j][q];
                ps = fmaf(v, asc[j], ps);
                pd = fmaf(v, adc[j], pd);
            }
            #pragma unroll
            for (int o = 1; o < 16; o <<= 1) {
                ps += __shfl_xor(ps, o, 64);
                pd += __shfl_xor(pd, o, 64);
            }
            int rl = rbase + i * 16 + hi4 * 4 + q;
            if constexpr (DCOLS == 256) {
                int row = n0 + rl;
                if (l16 == 0 && row < M) {
                    alpha_s[row * HEADS + w] = ps;
                    alpha_d[row * HEADS + w] = pd;
                }
            } else {
                if (l16 == 0) { as_l[rl][ct] = ps; ad_l[rl][ct] = pd; }
            }
        }
    if constexpr (DCOLS == 128) {
        __syncthreads();
        int t = threadIdx.x;
        if (t < 128) {
            int row = n0 + t;
            if (row < M) {
                alpha_s[row] = as_l[t][0] + as_l[t][1];
                alpha_d[row] = ad_l[t][0] + ad_l[t][1];
            }
        }
    }
}

// ================= CSR build (once per call) =================
__global__ void deg_count_kernel(const int* __restrict__ ei, int* __restrict__ deg,
                                 int E, int Etot) {
    int e = blockIdx.x * blockDim.x + threadIdx.x;
    if (e >= Etot) return;
    int d = (e < E) ? ei[E + e] : e - E;
    atomicAdd(&deg[d], 1);
}

#define SCB 4096
__global__ __launch_bounds__(256) void scan1_kernel(const int* __restrict__ deg,
                                                    int* __restrict__ bsum, int N) {
    __shared__ int ts[256];
    const int t = threadIdx.x;
    const int base = blockIdx.x * SCB + t * 16;
    int s = 0;
    #pragma unroll
    for (int i = 0; i < 16; ++i) {
        int idx = base + i;
        if (idx < N) s += deg[idx];
    }
    ts[t] = s;
    __syncthreads();
    for (int off = 128; off > 0; off >>= 1) {
        if (t < off) ts[t] += ts[t + off];
        __syncthreads();
    }
    if (t == 0) bsum[blockIdx.x] = ts[0];
}

__global__ __launch_bounds__(256) void scan2_kernel(const int* __restrict__ bsum,
                                                    int* __restrict__ bpref, int B,
                                                    int* __restrict__ rowptrN) {
    __shared__ int sm[256];
    const int t = threadIdx.x;
    int v = (t < B) ? bsum[t] : 0;
    sm[t] = v;
    __syncthreads();
    for (int off = 1; off < 256; off <<= 1) {
        int u = (t >= off) ? sm[t - off] : 0;
        __syncthreads();
        sm[t] += u;
        __syncthreads();
    }
    if (t < B) bpref[t] = sm[t] - v;
    if (t == 255) *rowptrN = sm[255];
}

__global__ __launch_bounds__(256) void scan3_kernel(const int* __restrict__ deg,
                                                    const int* __restrict__ bpref,
                                                    int* __restrict__ rowptr,
                                                    int* __restrict__ cursor, int N) {
    __shared__ int ts[256];
    const int t = threadIdx.x;
    const int base = blockIdx.x * SCB + t * 16;
    int d[16];
    int s = 0;
    #pragma unroll
    for (int i = 0; i < 16; ++i) {
        int idx = base + i;
        d[i] = (idx < N) ? deg[idx] : 0;
        s += d[i];
    }
    ts[t] = s;
    __syncthreads();
    for (int off = 1; off < 256; off <<= 1) {
        int u = (t >= off) ? ts[t - off] : 0;
        __syncthreads();
        ts[t] += u;
        __syncthreads();
    }
    int run = bpref[blockIdx.x] + ts[t] - s;
    #pragma unroll
    for (int i = 0; i < 16; ++i) {
        int idx = base + i;
        if (idx < N) { rowptr[idx] = run; cursor[idx] = run; run += d[i]; }
    }
}

__global__ void scatter_kernel(const int* __restrict__ ei, int* __restrict__ cursor,
                               int* __restrict__ csrc, int E, int Etot) {
    int e = blockIdx.x * blockDim.x + threadIdx.x;
    if (e >= Etot) return;
    int s, d;
    if (e < E) { s = ei[e]; d = ei[E + e]; } else { s = d = e - E; }
    int pos = atomicAdd(&cursor[d], 1);
    csrc[pos] = s;
}

__global__ void gstart_kernel(const int* __restrict__ batch, int* __restrict__ gstart,
                              int N, int G) {
    int n = blockIdx.x * blockDim.x + threadIdx.x;
    if (n >= N) return;
    int b = batch[n];
    if (n == 0) { for (int g = 0; g <= b; ++g) gstart[g] = 0; }
    else {
        int bp = batch[n - 1];
        for (int g = bp + 1; g <= b; ++g) gstart[g] = n;
    }
    if (n == N - 1) { for (int g = b + 1; g <= G; ++g) gstart[g] = N; }
}

// ============ wave-per-node GAT edge phase, multi-edge gather ============
// LPE = D/8 lanes cover one row with dwordx4 (16B) loads; EPW = 64/LPE edges
// are processed concurrently by lane groups; partial sums merged by shfl_xor.
template<int HEADS, int C, bool GATE>
__global__ __launch_bounds__(256) void gat_agg(
    const int* __restrict__ rowptr, const int* __restrict__ csrc,
    const __bf16* __restrict__ hf, const float* __restrict__ asrc,
    const float* __restrict__ adst,
    const float* __restrict__ bias, const float* __restrict__ gamma,
    const float* __restrict__ beta, const float* __restrict__ mean,
    const float* __restrict__ var,
    __bf16* __restrict__ out,
    const float* __restrict__ pw1, const float* __restrict__ pb1,
    const float* __restrict__ pw2, const float* __restrict__ pb2,
    float* __restrict__ gateout, int N) {
    constexpr int D   = HEADS * C;
    constexpr int LPE = D / 8;      // lanes per edge (16B each)
    constexpr int EPW = 64 / LPE;   // edges in flight per wave-step

    const int wid  = threadIdx.x >> 6;
    const int lane = threadIdx.x & 63;
    const int node = blockIdx.x * 4 + wid;

    __shared__ int   soff[4][64];
    __shared__ float pal[4][64][HEADS];
    __shared__ float x4row[4][128];
    __shared__ float pw1s[GATE ? 128 * 32 : 1];

    if constexpr (GATE) {
        for (int i = threadIdx.x; i < 128 * 32; i += 256) pw1s[i] = pw1[i];
        __syncthreads();
    }

    if (node < N) {
        const int beg = rowptr[node], end = rowptr[node + 1];
        const int deg = end - beg;
        const int grp = lane / LPE;             // my edge-slot within a step
        const int c0  = (lane % LPE) * 8;       // my 8 columns
        const int hd  = c0 / C;                 // head of my columns
        const char* hb = (const char*)hf + (size_t)c0 * 2;

        float ad[HEADS];
        #pragma unroll
        for (int h = 0; h < HEADS; ++h) ad[h] = adst[node * HEADS + h];

        float acc8[8] = {};

        auto agg_chunk = [&](int cnt) {
            int e = 0;
            for (; e + 4 * EPW <= cnt; e += 4 * EPW) {
                int o0 = soff[wid][e + 0 * EPW + grp];
                int o1 = soff[wid][e + 1 * EPW + grp];
                int o2 = soff[wid][e + 2 * EPW + grp];
                int o3 = soff[wid][e + 3 * EPW + grp];
                float q0 = pal[wid][e + 0 * EPW + grp][hd];
                float q1 = pal[wid][e + 1 * EPW + grp][hd];
                float q2 = pal[wid][e + 2 * EPW + grp][hd];
                float q3 = pal[wid][e + 3 * EPW + grp][hd];
                bf16x8 v0 = *(const bf16x8*)(hb + o0);
                bf16x8 v1 = *(const bf16x8*)(hb + o1);
                bf16x8 v2 = *(const bf16x8*)(hb + o2);
                bf16x8 v3 = *(const bf16x8*)(hb + o3);
                #pragma unroll
                for (int i = 0; i < 8; ++i) {
                    acc8[i] = fmaf((float)v0[i], q0, acc8[i]);
                    acc8[i] = fmaf((float)v1[i], q1, acc8[i]);
                    acc8[i] = fmaf((float)v2[i], q2, acc8[i]);
                    acc8[i] = fmaf((float)v3[i], q3, acc8[i]);
                }
            }
            for (; e + EPW <= cnt; e += EPW) {
                int o0 = soff[wid][e + grp];
                float q0 = pal[wid][e + grp][hd];
                bf16x8 v0 = *(const bf16x8*)(hb + o0);
                #pragma unroll
                for (int i = 0; i < 8; ++i)
                    acc8[i] = fmaf((float)v0[i], q0, acc8[i]);
            }
            if (e < cnt) {
                int r = cnt - e;                 // 1..EPW-1
                int o0 = soff[wid][(grp < r) ? e + grp : e];
                float q0 = (grp < r) ? pal[wid][e + grp][hd] : 0.f;
                bf16x8 v0 = *(const bf16x8*)(hb + o0);
                #pragma unroll
                for (int i = 0; i < 8; ++i)
                    acc8[i] = fmaf((float)v0[i], q0, acc8[i]);
            }
        };

        if (deg <= 64) {
            // ---- logits: lane = edge slot ----
            const bool act = lane < deg;
            int msrc = act ? csrc[beg + lane] : 0;
            float lv[HEADS];
            if constexpr (HEADS == 4) {
                float4 a4 = ((const float4*)asrc)[msrc];
                lv[0] = a4.x; lv[1] = a4.y; lv[2] = a4.z; lv[3] = a4.w;
            } else {
                lv[0] = asrc[msrc];
            }
            float p[HEADS];
            #pragma unroll
            for (int h = 0; h < HEADS; ++h) {
                float v;
                if (act) { v = lv[h] + ad[h]; v = v > 0.f ? v : NEG_SLOPE * v; }
                else v = -INFINITY;
                float mx = v;
                #pragma unroll
                for (int o = 1; o < 64; o <<= 1) mx = fmaxf(mx, __shfl_xor(mx, o, 64));
                float pe = act ? __expf(v - mx) : 0.f;
                float ps = pe;
                #pragma unroll
                for (int o = 1; o < 64; o <<= 1) ps += __shfl_xor(ps, o, 64);
                p[h] = pe * (1.f / (ps + 1e-16f));
            }
            soff[wid][lane] = msrc * (D * 2);
            if constexpr (HEADS == 4)
                *(float4*)&pal[wid][lane][0] = make_float4(p[0], p[1], p[2], p[3]);
            else
                pal[wid][lane][0] = p[0];
            asm volatile("s_waitcnt lgkmcnt(0)" ::: "memory");
            agg_chunk(deg);
        } else {
            // ---- general path (deg > 64; rare) ----
            float mx[HEADS], sm[HEADS], inv[HEADS];
            #pragma unroll
            for (int h = 0; h < HEADS; ++h) mx[h] = -INFINITY;
            for (int j = beg + lane; j < end; j += 64) {
                int s = csrc[j];
                #pragma unroll
                for (int h = 0; h < HEADS; ++h) {
                    float v = asrc[s * HEADS + h] + ad[h];
                    v = v > 0.f ? v : NEG_SLOPE * v;
                    mx[h] = fmaxf(mx[h], v);
                }
            }
            #pragma unroll
            for (int h = 0; h < HEADS; ++h) {
                #pragma unroll
                for (int o = 1; o < 64; o <<= 1) mx[h] = fmaxf(mx[h], __shfl_xor(mx[h], o, 64));
                sm[h] = 0.f;
            }
            for (int j = beg + lane; j < end; j += 64) {
                int s = csrc[j];
                #pragma unroll
                for (int h = 0; h < HEADS; ++h) {
                    float v = asrc[s * HEADS + h] + ad[h];
                    v = v > 0.f ? v : NEG_SLOPE * v;
                    sm[h] += __expf(v - mx[h]);
                }
            }
            #pragma unroll
            for (int h = 0; h < HEADS; ++h) {
                #pragma unroll
                for (int o = 1; o < 64; o <<= 1) sm[h] += __shfl_xor(sm[h], o, 64);
                inv[h] = 1.f / (sm[h] + 1e-16f);
            }
            for (int base2 = beg; base2 < end; base2 += 64) {
                int ne = min(64, end - base2);
                bool act2 = lane < ne;
                int msrc = csrc[base2 + (act2 ? lane : 0)];
                soff[wid][lane] = msrc * (D * 2);
                #pragma unroll
                for (int h = 0; h < HEADS; ++h) {
                    float pv = 0.f;
                    if (act2) {
                        float v = asrc[msrc * HEADS + h] + ad[h];
                        v = v > 0.f ? v : NEG_SLOPE * v;
                        pv = __expf(v - mx[h]) * inv[h];
                    }
                    pal[wid][lane][h] = pv;
                }
                asm volatile("s_waitcnt lgkmcnt(0)" ::: "memory");
                agg_chunk(ne);
                asm volatile("s_waitcnt lgkmcnt(0)" ::: "memory");
            }
        }

        // ---- merge edge-group partials: lanes l, l^LPE, ... own same cols ----
        #pragma unroll
        for (int o = LPE; o < 64; o <<= 1)
            #pragma unroll
            for (int i = 0; i < 8; ++i)
                acc8[i] += __shfl_xor(acc8[i], o, 64);

        // ---- epilogue: bias + BN(inference) + ReLU -> bf16 ----
        if (lane < LPE) {
            bf16x8 ov;
            #pragma unroll
            for (int i = 0; i < 8; ++i) {
                int c = c0 + i;
                float v = acc8[i] + bias[c];
                v = (v - mean[c]) * rsqrtf(var[c] + BN_EPS) * gamma[c] + beta[c];
                v = fmaxf(v, 0.f);
                ov[i] = (__bf16)v;
                if constexpr (GATE) x4row[wid][c] = v;
            }
            *(bf16x8*)&out[(size_t)node * D + c0] = ov;
        }

        if constexpr (GATE) {
            asm volatile("s_waitcnt lgkmcnt(0)" ::: "memory");
            const int j = lane & 31;
            const int half = lane >> 5;
            float p = 0.f;
            const float* xr = &x4row[wid][half * 64];
            const float* pwb = &pw1s[half * 64 * 32 + j];
            #pragma unroll 16
            for (int cc = 0; cc < 64; ++cc)
                p = fmaf(xr[cc], pwb[cc * 32], p);
            p += __shfl_xor(p, 32, 64);
            float g = fmaxf(p + pb1[j], 0.f) * pw2[j];
            #pragma unroll
            for (int o = 1; o < 32; o <<= 1) g += __shfl_xor(g, o, 64);
            if (lane == 0) gateout[node] = g + pb2[0];
        }
    }
}

// ---------- block-per-graph pooling ----------
__global__ __launch_bounds__(128) void pool_kernel(
    const __bf16* __restrict__ x4, const float* __restrict__ gate,
    const int* __restrict__ gstart, float* __restrict__ out) {
    const int g = blockIdx.x;
    const int t = threadIdx.x;
    const int beg = gstart[g], end = gstart[g + 1];
    __shared__ float red[128];
    __shared__ float wbuf[128];
    float m = -INFINITY;
    for (int n = beg + t; n < end; n += 128) m = fmaxf(m, gate[n]);
    red[t] = m; __syncthreads();
    for (int off = 64; off > 0; off >>= 1) {
        if (t < off) red[t] = fmaxf(red[t], red[t + off]);
        __syncthreads();
    }
    m = red[0]; __syncthreads();
    float s = 0.f;
    for (int n = beg + t; n < end; n += 128) s += expf(gate[n] - m);
    red[t] = s; __syncthreads();
    for (int off = 64; off > 0; off >>= 1) {
        if (t < off) red[t] += red[t + off];
        __syncthreads();
    }
    const float inv = 1.f / (red[0] + 1e-16f);
    __syncthreads();
    float acc = 0.f;
    for (int base = beg; base < end; base += 128) {
        int ne = min(128, end - base);
        if (t < ne) wbuf[t] = expf(gate[base + t] - m) * inv;
        __syncthreads();
        for (int i = 0; i < ne; ++i)
            acc = fmaf(wbuf[i], (float)x4[(size_t)(base + i) * 128 + t], acc);
        __syncthreads();
    }
    out[(size_t)g * 160 + t] = acc;
}

// ---------- global-feature MLP into d_out[:, 128:160] ----------
__global__ void gfeat_kernel(const float* __restrict__ gfeat,
                             const float* __restrict__ gw, const float* __restrict__ gb,
                             float* __restrict__ out) {
    const int g = blockIdx.x;
    const int k = threadIdx.x;
    if (k < 32) {
        float t = gb[k];
        #pragma unroll
        for (int j = 0; j < 7; ++j) t = fmaf(gfeat[g * 7 + j], gw[j * 32 + k], t);
        out[(size_t)g * 160 + 128 + k] = fmaxf(t, 0.f);
    }
}

// ==========================================================================
extern "C" void kernel_launch(void* const* d_in, const int* in_sizes, int n_in,
                              void* d_out, int out_size, void* d_ws, size_t ws_size,
                              hipStream_t stream) {
    const float* x      = (const float*)d_in[0];
    const int*   ei     = (const int*)  d_in[1];
    const int*   batch  = (const int*)  d_in[2];
    const float* gfeat  = (const float*)d_in[3];

    const int N    = in_sizes[2];
    const int E    = in_sizes[1] / 2;
    const int G    = in_sizes[3] / 7;
    const int IN   = in_sizes[0] / N;
    const int Etot = E + N;
    const int INp  = 64;

    const float* W[4];  const float* avs[4]; const float* avd[4]; const float* bi[4];
    const float* ga[4]; const float* be[4];  const float* mu[4];  const float* va[4];
    for (int l = 0; l < 4; ++l) {
        int o = 4 + 8 * l;
        W[l]   = (const float*)d_in[o + 0];
        avs[l] = (const float*)d_in[o + 1];
        avd[l] = (const float*)d_in[o + 2];
        bi[l]  = (const float*)d_in[o + 3];
        ga[l]  = (const float*)d_in[o + 4];
        be[l]  = (const float*)d_in[o + 5];
        mu[l]  = (const float*)d_in[o + 6];
        va[l]  = (const float*)d_in[o + 7];
    }
    const float* pw1 = (const float*)d_in[36];
    const float* pb1 = (const float*)d_in[37];
    const float* pw2 = (const float*)d_in[38];
    const float* pb2 = (const float*)d_in[39];
    const float* gw  = (const float*)d_in[40];
    const float* gb  = (const float*)d_in[41];

    float* out = (float*)d_out;

    float* ws = (float*)d_ws;
    __bf16* xb = (__bf16*)ws; ws += (size_t)N * 32;
    __bf16* h  = (__bf16*)ws; ws += (size_t)N * 128;
    __bf16* x1 = (__bf16*)ws; ws += (size_t)N * 128;
    __bf16* x2 = (__bf16*)ws; ws += (size_t)N * 128;
    __bf16* x3 = (__bf16*)ws; ws += (size_t)N * 128;
    __bf16* wt1 = (__bf16*)ws; ws += 256 * 64 / 2;
    __bf16* wt2 = (__bf16*)ws; ws += 256 * 256 / 2;
    __bf16* wt3 = (__bf16*)ws; ws += 256 * 256 / 2;
    __bf16* wt4 = (__bf16*)ws; ws += 128 * 256 / 2;
    float* asrc = ws;  ws += (size_t)N * 4;
    float* adst = ws;  ws += (size_t)N * 4;
    float* gate = ws;  ws += N;
    int* deg    = (int*)ws; ws += N;
    int* cursor = (int*)ws; ws += N;
    int* rowptr = (int*)ws; ws += (N + 1);
    int* csrc   = (int*)ws; ws += Etot;
    int* gstart = (int*)ws; ws += (G + 1);
    int* bsum   = (int*)ws; ws += 256;
    int* bpref  = (int*)ws; ws += 256;
    __bf16* x4 = x1;

    const int SB = (N + SCB - 1) / SCB;

    hipLaunchKernelGGL(conv_pad_kernel, dim3(512), dim3(256), 0, stream, x, xb, N, IN, INp);
    hipLaunchKernelGGL(wtrans_all_kernel, dim3(896), dim3(256), 0, stream,
                       W[0], W[1], W[2], W[3], wt1, wt2, wt3, wt4, IN);

    hipMemsetAsync(deg, 0, (size_t)N * 4, stream);
    hipLaunchKernelGGL(deg_count_kernel, dim3((Etot + 255) / 256), dim3(256), 0, stream,
                       ei, deg, E, Etot);
    hipLaunchKernelGGL(scan1_kernel, dim3(SB), dim3(256), 0, stream, deg, bsum, N);
    hipLaunchKernelGGL(scan2_kernel, dim3(1), dim3(256), 0, stream, bsum, bpref, SB,
                       &rowptr[N]);
    hipLaunchKernelGGL(scan3_kernel, dim3(SB), dim3(256), 0, stream, deg, bpref,
                       rowptr, cursor, N);
    hipLaunchKernelGGL(scatter_kernel, dim3((Etot + 255) / 256), dim3(256), 0, stream,
                       ei, cursor, csrc, E, Etot);
    hipLaunchKernelGGL(gstart_kernel, dim3((N + 255) / 256), dim3(256), 0, stream,
                       batch, gstart, N, G);

    const int grid256 = (N + 63) / 64;
    const int grid128 = (N + 127) / 128;
    const int gatgrid = (N + 3) / 4;

    hipLaunchKernelGGL((gemm_fused<256, 4, false>), dim3(grid256), dim3(256), 0, stream,
                       xb, nullptr, wt1, avs[0], avd[0], h, asrc, adst, N, INp);
    hipLaunchKernelGGL((gat_agg<4, 64, false>), dim3(gatgrid), dim3(256), 0, stream,
                       rowptr, csrc, h, asrc, adst, bi[0], ga[0], be[0], mu[0], va[0], x1,
                       nullptr, nullptr, nullptr, nullptr, nullptr, N);
    hipLaunchKernelGGL((gemm_fused<256, 4, false>), dim3(grid256), dim3(256), 0, stream,
                       x1, nullptr, wt2, avs[1], avd[1], h, asrc, adst, N, 256);
    hipLaunchKernelGGL((gat_agg<4, 64, false>), dim3(gatgrid), dim3(256), 0, stream,
                       rowptr, csrc, h, asrc, adst, bi[1], ga[1], be[1], mu[1], va[1], x2,
                       nullptr, nullptr, nullptr, nullptr, nullptr, N);
    hipLaunchKernelGGL((gemm_fused<256, 4, true>), dim3(grid256), dim3(256), 0, stream,
                       x1, x2, wt3, avs[2], avd[2], h, asrc, adst, N, 256);
    hipLaunchKernelGGL((gat_agg<4, 64, false>), dim3(gatgrid), dim3(256), 0, stream,
                       rowptr, csrc, h, asrc, adst, bi[2], ga[2], be[2], mu[2], va[2], x3,
                       nullptr, nullptr, nullptr, nullptr, nullptr, N);
    hipLaunchKernelGGL((gemm_fused<128, 1, false>), dim3(grid128), dim3(256), 0, stream,
                       x3, nullptr, wt4, avs[3], avd[3], h, asrc, adst, N, 256);
    hipLaunchKernelGGL((gat_agg<1, 128, true>), dim3(gatgrid), dim3(256), 0, stream,
                       rowptr, csrc, h, asrc, adst, bi[3], ga[3], be[3], mu[3], va[3], x4,
                       pw1, pb1, pw2, pb2, gate, N);

    hipLaunchKernelGGL(pool_kernel, dim3(G), dim3(128), 0, stream, x4, gate, gstart, out);
    hipLaunchKernelGGL(gfeat_kernel, dim3(G), dim3(64), 0, stream, gfeat, gw, gb, out);
}

// Round 10
// 545.440 us; speedup vs baseline: 1.0635x; 1.0635x over previous
//
#include <hip/hip_runtime.h>
#include <cstdint>
#include <cstddef>

#define NEG_SLOPE 0.2f
#define BN_EPS 1e-5f

typedef __bf16 bf16x8 __attribute__((ext_vector_type(8)));
typedef float  f32x4  __attribute__((ext_vector_type(4)));

// ---------- prep: x fp32 [N][K] -> bf16 [N][Kpad] zero-padded ----------
__global__ void conv_pad_kernel(const float* __restrict__ x, __bf16* __restrict__ xb,
                                int N, int K, int Kpad) {
    int i = blockIdx.x * blockDim.x + threadIdx.x;
    int total = N * Kpad;
    for (; i < total; i += gridDim.x * blockDim.x) {
        int n = i / Kpad, k = i - n * Kpad;
        xb[i] = (k < K) ? (__bf16)x[(size_t)n * K + k] : (__bf16)0.f;
    }
}

// ---------- prep: all 4 weight transposes in one launch ----------
__global__ void wtrans_all_kernel(const float* __restrict__ W1, const float* __restrict__ W2,
                                  const float* __restrict__ W3, const float* __restrict__ W4,
                                  __bf16* __restrict__ wt1, __bf16* __restrict__ wt2,
                                  __bf16* __restrict__ wt3, __bf16* __restrict__ wt4, int IN) {
    int b = blockIdx.x;
    const float* W; __bf16* WT; int K, D, Kpad, col;
    if (b < 256)      { W = W1; WT = wt1; K = IN;  D = 256; Kpad = 64;  col = b; }
    else if (b < 512) { W = W2; WT = wt2; K = 256; D = 256; Kpad = 256; col = b - 256; }
    else if (b < 768) { W = W3; WT = wt3; K = 256; D = 256; Kpad = 256; col = b - 512; }
    else              { W = W4; WT = wt4; K = 256; D = 128; Kpad = 256; col = b - 768; }
    for (int k = threadIdx.x; k < Kpad; k += blockDim.x)
        WT[(size_t)col * Kpad + k] = (k < K) ? (__bf16)W[(size_t)k * D + col] : (__bf16)0.f;
}

// ================= LDS-free MFMA GEMM strip + fused alpha + int8-quant H ====
// Output H is int8 with per-row scale hscale[row] = rowmax/127. Alpha logits
// are computed from the fp32 accumulators (full precision).
template<int DCOLS, int HEADS, bool HAS_A2>
__global__ __launch_bounds__(256) void gemm_fused(
    const __bf16* __restrict__ A, const __bf16* __restrict__ A2,
    const __bf16* __restrict__ WT,
    const float* __restrict__ asv, const float* __restrict__ adv,
    int8_t* __restrict__ H8, float* __restrict__ hscale,
    float* __restrict__ alpha_s, float* __restrict__ alpha_d,
    int M, int K) {
    constexpr int RB = (DCOLS == 256) ? 64 : 128;
    constexpr int NW = (DCOLS == 256) ? 4 : 2;     // waves sharing each row
    const int w    = threadIdx.x >> 6;
    const int lane = threadIdx.x & 63;
    const int l16  = lane & 15, hi4 = lane >> 4;
    const int rg    = (DCOLS == 256) ? 0 : (w >> 1);
    const int ct    = (DCOLS == 256) ? w : (w & 1);
    const int col0w = ct * 64;
    const int rbase = rg * 64;
    const int n0 = blockIdx.x * RB;
    const int lk = hi4 * 8;

    f32x4 acc[4][4] = {};
    int arow[4];
    #pragma unroll
    for (int i = 0; i < 4; ++i) {
        int r = n0 + rbase + i * 16 + l16;
        arow[i] = (r < M) ? r : (M - 1);
    }

    for (int k0 = 0; k0 < K; k0 += 32) {
        bf16x8 af[4], bfr[4];
        #pragma unroll
        for (int i = 0; i < 4; ++i) {
            bf16x8 v = *(const bf16x8*)&A[(size_t)arow[i] * K + k0 + lk];
            if (HAS_A2) {
                bf16x8 v2 = *(const bf16x8*)&A2[(size_t)arow[i] * K + k0 + lk];
                #pragma unroll
                for (int j = 0; j < 8; ++j) v[j] = (__bf16)((float)v[j] + (float)v2[j]);
            }
            af[i] = v;
        }
        #pragma unroll
        for (int j = 0; j < 4; ++j)
            bfr[j] = *(const bf16x8*)&WT[(size_t)(col0w + j * 16 + l16) * K + k0 + lk];
        #pragma unroll
        for (int i = 0; i < 4; ++i)
            #pragma unroll
            for (int j = 0; j < 4; ++j)
                acc[i][j] = __builtin_amdgcn_mfma_f32_16x16x32_bf16(
                    af[i], bfr[j], acc[i][j], 0, 0, 0);
    }

    // ---- fused alpha: per-row dot with a_src / a_dst over this wave's 64 cols ----
    float asc[4], adc[4];
    #pragma unroll
    for (int j = 0; j < 4; ++j) {
        int c = col0w + j * 16 + l16;
        asc[j] = asv[c]; adc[j] = adv[c];
    }
    __shared__ float as_l[128][2], ad_l[128][2];
    __shared__ float rmaxl[RB][NW];
    #pragma unroll
    for (int i = 0; i < 4; ++i)
        #pragma unroll
        for (int q = 0; q < 4; ++q) {
            float ps = 0.f, pd = 0.f;
            #pragma unroll
            for (int j = 0; j < 4; ++j) {
                float v = acc[i][j][q];
                ps = fmaf(v, asc[j], ps);
                pd = fmaf(v, adc[j], pd);
            }
            #pragma unroll
            for (int o = 1; o < 16; o <<= 1) {
                ps += __shfl_xor(ps, o, 64);
                pd += __shfl_xor(pd, o, 64);
            }
            int rl = rbase + i * 16 + hi4 * 4 + q;
            if constexpr (DCOLS == 256) {
                int row = n0 + rl;
                if (l16 == 0 && row < M) {
                    alpha_s[row * HEADS + w] = ps;
                    alpha_d[row * HEADS + w] = pd;
                }
            } else {
                if (l16 == 0) { as_l[rl][ct] = ps; ad_l[rl][ct] = pd; }
            }
        }

    // ---- per-row max(|acc|) for int8 quantization ----
    float rm[4][4];
    #pragma unroll
    for (int i = 0; i < 4; ++i)
        #pragma unroll
        for (int q = 0; q < 4; ++q) {
            float m = fabsf(acc[i][0][q]);
            #pragma unroll
            for (int j = 1; j < 4; ++j) m = fmaxf(m, fabsf(acc[i][j][q]));
            rm[i][q] = m;
        }
    #pragma unroll
    for (int o = 1; o < 16; o <<= 1)
        #pragma unroll
        for (int i = 0; i < 4; ++i)
            #pragma unroll
            for (int q = 0; q < 4; ++q)
                rm[i][q] = fmaxf(rm[i][q], __shfl_xor(rm[i][q], o, 64));
    if (l16 == 0) {
        #pragma unroll
        for (int i = 0; i < 4; ++i)
            #pragma unroll
            for (int q = 0; q < 4; ++q)
                rmaxl[rbase + i * 16 + hi4 * 4 + q][(DCOLS == 256) ? w : ct] = rm[i][q];
    }
    __syncthreads();

    if constexpr (DCOLS == 128) {
        int t = threadIdx.x;
        if (t < 128) {
            int row = n0 + t;
            if (row < M) {
                alpha_s[row] = as_l[t][0] + as_l[t][1];
                alpha_d[row] = ad_l[t][0] + ad_l[t][1];
            }
        }
    }

    // ---- quantize + store int8 H and per-row scale ----
    #pragma unroll
    for (int i = 0; i < 4; ++i)
        #pragma unroll
        for (int q = 0; q < 4; ++q) {
            int rl = rbase + i * 16 + hi4 * 4 + q;
            float m4 = rmaxl[rl][0];
            #pragma unroll
            for (int k = 1; k < NW; ++k) m4 = fmaxf(m4, rmaxl[rl][k]);
            float qinv = (m4 > 1e-30f) ? 127.f / m4 : 0.f;
            int row = n0 + rl;
            if (row < M) {
                if (l16 == 0 && ct == 0 && (DCOLS == 128 || w == 0))
                    hscale[row] = m4 * (1.f / 127.f);
                #pragma unroll
                for (int j = 0; j < 4; ++j)
                    H8[(size_t)row * DCOLS + col0w + j * 16 + l16] =
                        (int8_t)rintf(acc[i][j][q] * qinv);
            }
        }
}

// ================= CSR build (once per call) =================
__global__ void deg_count_kernel(const int* __restrict__ ei, int* __restrict__ deg,
                                 int E, int Etot) {
    int e = blockIdx.x * blockDim.x + threadIdx.x;
    if (e >= Etot) return;
    int d = (e < E) ? ei[E + e] : e - E;
    atomicAdd(&deg[d], 1);
}

#define SCB 4096
__global__ __launch_bounds__(256) void scan1_kernel(const int* __restrict__ deg,
                                                    int* __restrict__ bsum, int N) {
    __shared__ int ts[256];
    const int t = threadIdx.x;
    const int base = blockIdx.x * SCB + t * 16;
    int s = 0;
    #pragma unroll
    for (int i = 0; i < 16; ++i) {
        int idx = base + i;
        if (idx < N) s += deg[idx];
    }
    ts[t] = s;
    __syncthreads();
    for (int off = 128; off > 0; off >>= 1) {
        if (t < off) ts[t] += ts[t + off];
        __syncthreads();
    }
    if (t == 0) bsum[blockIdx.x] = ts[0];
}

__global__ __launch_bounds__(256) void scan2_kernel(const int* __restrict__ bsum,
                                                    int* __restrict__ bpref, int B,
                                                    int* __restrict__ rowptrN) {
    __shared__ int sm[256];
    const int t = threadIdx.x;
    int v = (t < B) ? bsum[t] : 0;
    sm[t] = v;
    __syncthreads();
    for (int off = 1; off < 256; off <<= 1) {
        int u = (t >= off) ? sm[t - off] : 0;
        __syncthreads();
        sm[t] += u;
        __syncthreads();
    }
    if (t < B) bpref[t] = sm[t] - v;
    if (t == 255) *rowptrN = sm[255];
}

__global__ __launch_bounds__(256) void scan3_kernel(const int* __restrict__ deg,
                                                    const int* __restrict__ bpref,
                                                    int* __restrict__ rowptr,
                                                    int* __restrict__ cursor, int N) {
    __shared__ int ts[256];
    const int t = threadIdx.x;
    const int base = blockIdx.x * SCB + t * 16;
    int d[16];
    int s = 0;
    #pragma unroll
    for (int i = 0; i < 16; ++i) {
        int idx = base + i;
        d[i] = (idx < N) ? deg[idx] : 0;
        s += d[i];
    }
    ts[t] = s;
    __syncthreads();
    for (int off = 1; off < 256; off <<= 1) {
        int u = (t >= off) ? ts[t - off] : 0;
        __syncthreads();
        ts[t] += u;
        __syncthreads();
    }
    int run = bpref[blockIdx.x] + ts[t] - s;
    #pragma unroll
    for (int i = 0; i < 16; ++i) {
        int idx = base + i;
        if (idx < N) { rowptr[idx] = run; cursor[idx] = run; run += d[i]; }
    }
}

__global__ void scatter_kernel(const int* __restrict__ ei, int* __restrict__ cursor,
                               int* __restrict__ csrc, int E, int Etot) {
    int e = blockIdx.x * blockDim.x + threadIdx.x;
    if (e >= Etot) return;
    int s, d;
    if (e < E) { s = ei[e]; d = ei[E + e]; } else { s = d = e - E; }
    int pos = atomicAdd(&cursor[d], 1);
    csrc[pos] = s;
}

__global__ void gstart_kernel(const int* __restrict__ batch, int* __restrict__ gstart,
                              int N, int G) {
    int n = blockIdx.x * blockDim.x + threadIdx.x;
    if (n >= N) return;
    int b = batch[n];
    if (n == 0) { for (int g = 0; g <= b; ++g) gstart[g] = 0; }
    else {
        int bp = batch[n - 1];
        for (int g = bp + 1; g <= b; ++g) gstart[g] = n;
    }
    if (n == N - 1) { for (int g = b + 1; g <= G; ++g) gstart[g] = N; }
}

// ============ wave-per-node GAT edge phase, int8-h gather ============
// h rows are int8 with per-src-row scale; the scale is folded into palpha, so
// the gather loop is sext-byte + cvt + fma. Softmax logits remain fp32.
template<int HEADS, int C, bool GATE>
__global__ __launch_bounds__(256) void gat_agg(
    const int* __restrict__ rowptr, const int* __restrict__ csrc,
    const int8_t* __restrict__ hf, const float* __restrict__ hscale,
    const float* __restrict__ asrc, const float* __restrict__ adst,
    const float* __restrict__ bias, const float* __restrict__ gamma,
    const float* __restrict__ beta, const float* __restrict__ mean,
    const float* __restrict__ var,
    __bf16* __restrict__ out,
    const float* __restrict__ pw1, const float* __restrict__ pb1,
    const float* __restrict__ pw2, const float* __restrict__ pb2,
    float* __restrict__ gateout, int N) {
    constexpr int D   = HEADS * C;
    constexpr int LPE = D / 8;      // lanes per edge (8 cols x 1B each)
    constexpr int EPW = 64 / LPE;   // edges in flight per wave-step

    const int wid  = threadIdx.x >> 6;
    const int lane = threadIdx.x & 63;
    const int node = blockIdx.x * 4 + wid;

    __shared__ int   soff[4][64];
    __shared__ float pal[4][64][HEADS];
    __shared__ float x4row[4][128];
    __shared__ float pw1s[GATE ? 128 * 32 : 1];

    if constexpr (GATE) {
        for (int i = threadIdx.x; i < 128 * 32; i += 256) pw1s[i] = pw1[i];
        __syncthreads();
    }

    union C8 { int2 w; int8_t b[8]; };

    if (node < N) {
        const int beg = rowptr[node], end = rowptr[node + 1];
        const int deg = end - beg;
        const int grp = lane / LPE;             // my edge-slot within a step
        const int c0  = (lane % LPE) * 8;       // my 8 columns
        const int hd  = c0 / C;                 // head of my columns
        const int8_t* hb = hf + c0;

        float ad[HEADS];
        #pragma unroll
        for (int h = 0; h < HEADS; ++h) ad[h] = adst[node * HEADS + h];

        float acc8[8] = {};

        auto agg_chunk = [&](int cnt) {
            int e = 0;
            for (; e + 4 * EPW <= cnt; e += 4 * EPW) {
                int o0 = soff[wid][e + 0 * EPW + grp];
                int o1 = soff[wid][e + 1 * EPW + grp];
                int o2 = soff[wid][e + 2 * EPW + grp];
                int o3 = soff[wid][e + 3 * EPW + grp];
                float q0 = pal[wid][e + 0 * EPW + grp][hd];
                float q1 = pal[wid][e + 1 * EPW + grp][hd];
                float q2 = pal[wid][e + 2 * EPW + grp][hd];
                float q3 = pal[wid][e + 3 * EPW + grp][hd];
                C8 v0, v1, v2, v3;
                v0.w = *(const int2*)(hb + o0);
                v1.w = *(const int2*)(hb + o1);
                v2.w = *(const int2*)(hb + o2);
                v3.w = *(const int2*)(hb + o3);
                #pragma unroll
                for (int i = 0; i < 8; ++i) {
                    acc8[i] = fmaf((float)v0.b[i], q0, acc8[i]);
                    acc8[i] = fmaf((float)v1.b[i], q1, acc8[i]);
                    acc8[i] = fmaf((float)v2.b[i], q2, acc8[i]);
                    acc8[i] = fmaf((float)v3.b[i], q3, acc8[i]);
                }
            }
            for (; e + EPW <= cnt; e += EPW) {
                int o0 = soff[wid][e + grp];
                float q0 = pal[wid][e + grp][hd];
                C8 v0; v0.w = *(const int2*)(hb + o0);
                #pragma unroll
                for (int i = 0; i < 8; ++i)
                    acc8[i] = fmaf((float)v0.b[i], q0, acc8[i]);
            }
            if (e < cnt) {
                int r = cnt - e;
                int o0 = soff[wid][(grp < r) ? e + grp : e];
                float q0 = (grp < r) ? pal[wid][e + grp][hd] : 0.f;
                C8 v0; v0.w = *(const int2*)(hb + o0);
                #pragma unroll
                for (int i = 0; i < 8; ++i)
                    acc8[i] = fmaf((float)v0.b[i], q0, acc8[i]);
            }
        };

        if (deg <= 64) {
            // ---- logits: lane = edge slot ----
            const bool act = lane < deg;
            int msrc = act ? csrc[beg + lane] : 0;
            float hs = act ? hscale[msrc] : 0.f;
            float lv[HEADS];
            if constexpr (HEADS == 4) {
                float4 a4 = ((const float4*)asrc)[msrc];
                lv[0] = a4.x; lv[1] = a4.y; lv[2] = a4.z; lv[3] = a4.w;
            } else {
                lv[0] = asrc[msrc];
            }
            float p[HEADS];
            #pragma unroll
            for (int h = 0; h < HEADS; ++h) {
                float v;
                if (act) { v = lv[h] + ad[h]; v = v > 0.f ? v : NEG_SLOPE * v; }
                else v = -INFINITY;
                float mx = v;
                #pragma unroll
                for (int o = 1; o < 64; o <<= 1) mx = fmaxf(mx, __shfl_xor(mx, o, 64));
                float pe = act ? __expf(v - mx) : 0.f;
                float ps = pe;
                #pragma unroll
                for (int o = 1; o < 64; o <<= 1) ps += __shfl_xor(ps, o, 64);
                p[h] = pe * (1.f / (ps + 1e-16f)) * hs;   // fold src row scale
            }
            soff[wid][lane] = msrc * D;
            if constexpr (HEADS == 4)
                *(float4*)&pal[wid][lane][0] = make_float4(p[0], p[1], p[2], p[3]);
            else
                pal[wid][lane][0] = p[0];
            asm volatile("s_waitcnt lgkmcnt(0)" ::: "memory");
            agg_chunk(deg);
        } else {
            // ---- general path (deg > 64; rare) ----
            float mx[HEADS], sm[HEADS], inv[HEADS];
            #pragma unroll
            for (int h = 0; h < HEADS; ++h) mx[h] = -INFINITY;
            for (int j = beg + lane; j < end; j += 64) {
                int s = csrc[j];
                #pragma unroll
                for (int h = 0; h < HEADS; ++h) {
                    float v = asrc[s * HEADS + h] + ad[h];
                    v = v > 0.f ? v : NEG_SLOPE * v;
                    mx[h] = fmaxf(mx[h], v);
                }
            }
            #pragma unroll
            for (int h = 0; h < HEADS; ++h) {
                #pragma unroll
                for (int o = 1; o < 64; o <<= 1) mx[h] = fmaxf(mx[h], __shfl_xor(mx[h], o, 64));
                sm[h] = 0.f;
            }
            for (int j = beg + lane; j < end; j += 64) {
                int s = csrc[j];
                #pragma unroll
                for (int h = 0; h < HEADS; ++h) {
                    float v = asrc[s * HEADS + h] + ad[h];
                    v = v > 0.f ? v : NEG_SLOPE * v;
                    sm[h] += __expf(v - mx[h]);
                }
            }
            #pragma unroll
            for (int h = 0; h < HEADS; ++h) {
                #pragma unroll
                for (int o = 1; o < 64; o <<= 1) sm[h] += __shfl_xor(sm[h], o, 64);
                inv[h] = 1.f / (sm[h] + 1e-16f);
            }
            for (int base2 = beg; base2 < end; base2 += 64) {
                int ne = min(64, end - base2);
                bool act2 = lane < ne;
                int msrc = csrc[base2 + (act2 ? lane : 0)];
                float hs = act2 ? hscale[msrc] : 0.f;
                soff[wid][lane] = msrc * D;
                #pragma unroll
                for (int h = 0; h < HEADS; ++h) {
                    float pv = 0.f;
                    if (act2) {
                        float v = asrc[msrc * HEADS + h] + ad[h];
                        v = v > 0.f ? v : NEG_SLOPE * v;
                        pv = __expf(v - mx[h]) * inv[h] * hs;
                    }
                    pal[wid][lane][h] = pv;
                }
                asm volatile("s_waitcnt lgkmcnt(0)" ::: "memory");
                agg_chunk(ne);
                asm volatile("s_waitcnt lgkmcnt(0)" ::: "memory");
            }
        }

        // ---- merge edge-group partials ----
        #pragma unroll
        for (int o = LPE; o < 64; o <<= 1)
            #pragma unroll
            for (int i = 0; i < 8; ++i)
                acc8[i] += __shfl_xor(acc8[i], o, 64);

        // ---- epilogue: bias + BN(inference) + ReLU -> bf16 ----
        if (lane < LPE) {
            bf16x8 ov;
            #pragma unroll
            for (int i = 0; i < 8; ++i) {
                int c = c0 + i;
                float v = acc8[i] + bias[c];
                v = (v - mean[c]) * rsqrtf(var[c] + BN_EPS) * gamma[c] + beta[c];
                v = fmaxf(v, 0.f);
                ov[i] = (__bf16)v;
                if constexpr (GATE) x4row[wid][c] = v;
            }
            *(bf16x8*)&out[(size_t)node * D + c0] = ov;
        }

        if constexpr (GATE) {
            asm volatile("s_waitcnt lgkmcnt(0)" ::: "memory");
            const int j = lane & 31;
            const int half = lane >> 5;
            float p = 0.f;
            const float* xr = &x4row[wid][half * 64];
            const float* pwb = &pw1s[half * 64 * 32 + j];
            #pragma unroll 16
            for (int cc = 0; cc < 64; ++cc)
                p = fmaf(xr[cc], pwb[cc * 32], p);
            p += __shfl_xor(p, 32, 64);
            float g = fmaxf(p + pb1[j], 0.f) * pw2[j];
            #pragma unroll
            for (int o = 1; o < 32; o <<= 1) g += __shfl_xor(g, o, 64);
            if (lane == 0) gateout[node] = g + pb2[0];
        }
    }
}

// ---------- block-per-graph pooling ----------
__global__ __launch_bounds__(128) void pool_kernel(
    const __bf16* __restrict__ x4, const float* __restrict__ gate,
    const int* __restrict__ gstart, float* __restrict__ out) {
    const int g = blockIdx.x;
    const int t = threadIdx.x;
    const int beg = gstart[g], end = gstart[g + 1];
    __shared__ float red[128];
    __shared__ float wbuf[128];
    float m = -INFINITY;
    for (int n = beg + t; n < end; n += 128) m = fmaxf(m, gate[n]);
    red[t] = m; __syncthreads();
    for (int off = 64; off > 0; off >>= 1) {
        if (t < off) red[t] = fmaxf(red[t], red[t + off]);
        __syncthreads();
    }
    m = red[0]; __syncthreads();
    float s = 0.f;
    for (int n = beg + t; n < end; n += 128) s += expf(gate[n] - m);
    red[t] = s; __syncthreads();
    for (int off = 64; off > 0; off >>= 1) {
        if (t < off) red[t] += red[t + off];
        __syncthreads();
    }
    const float inv = 1.f / (red[0] + 1e-16f);
    __syncthreads();
    float acc = 0.f;
    for (int base = beg; base < end; base += 128) {
        int ne = min(128, end - base);
        if (t < ne) wbuf[t] = expf(gate[base + t] - m) * inv;
        __syncthreads();
        for (int i = 0; i < ne; ++i)
            acc = fmaf(wbuf[i], (float)x4[(size_t)(base + i) * 128 + t], acc);
        __syncthreads();
    }
    out[(size_t)g * 160 + t] = acc;
}

// ---------- global-feature MLP into d_out[:, 128:160] ----------
__global__ void gfeat_kernel(const float* __restrict__ gfeat,
                             const float* __restrict__ gw, const float* __restrict__ gb,
                             float* __restrict__ out) {
    const int g = blockIdx.x;
    const int k = threadIdx.x;
    if (k < 32) {
        float t = gb[k];
        #pragma unroll
        for (int j = 0; j < 7; ++j) t = fmaf(gfeat[g * 7 + j], gw[j * 32 + k], t);
        out[(size_t)g * 160 + 128 + k] = fmaxf(t, 0.f);
    }
}

// ==========================================================================
extern "C" void kernel_launch(void* const* d_in, const int* in_sizes, int n_in,
                              void* d_out, int out_size, void* d_ws, size_t ws_size,
                              hipStream_t stream) {
    const float* x      = (const float*)d_in[0];
    const int*   ei     = (const int*)  d_in[1];
    const int*   batch  = (const int*)  d_in[2];
    const float* gfeat  = (const float*)d_in[3];

    const int N    = in_sizes[2];
    const int E    = in_sizes[1] / 2;
    const int G    = in_sizes[3] / 7;
    const int IN   = in_sizes[0] / N;
    const int Etot = E + N;
    const int INp  = 64;

    const float* W[4];  const float* avs[4]; const float* avd[4]; const float* bi[4];
    const float* ga[4]; const float* be[4];  const float* mu[4];  const float* va[4];
    for (int l = 0; l < 4; ++l) {
        int o = 4 + 8 * l;
        W[l]   = (const float*)d_in[o + 0];
        avs[l] = (const float*)d_in[o + 1];
        avd[l] = (const float*)d_in[o + 2];
        bi[l]  = (const float*)d_in[o + 3];
        ga[l]  = (const float*)d_in[o + 4];
        be[l]  = (const float*)d_in[o + 5];
        mu[l]  = (const float*)d_in[o + 6];
        va[l]  = (const float*)d_in[o + 7];
    }
    const float* pw1 = (const float*)d_in[36];
    const float* pb1 = (const float*)d_in[37];
    const float* pw2 = (const float*)d_in[38];
    const float* pb2 = (const float*)d_in[39];
    const float* gw  = (const float*)d_in[40];
    const float* gb  = (const float*)d_in[41];

    float* out = (float*)d_out;

    float* ws = (float*)d_ws;
    __bf16* xb = (__bf16*)ws; ws += (size_t)N * 32;
    int8_t* h8 = (int8_t*)ws; ws += (size_t)N * 64;   // N x 256 int8
    float* hsc = ws;  ws += N;
    __bf16* x1 = (__bf16*)ws; ws += (size_t)N * 128;
    __bf16* x2 = (__bf16*)ws; ws += (size_t)N * 128;
    __bf16* x3 = (__bf16*)ws; ws += (size_t)N * 128;
    __bf16* wt1 = (__bf16*)ws; ws += 256 * 64 / 2;
    __bf16* wt2 = (__bf16*)ws; ws += 256 * 256 / 2;
    __bf16* wt3 = (__bf16*)ws; ws += 256 * 256 / 2;
    __bf16* wt4 = (__bf16*)ws; ws += 128 * 256 / 2;
    float* asrc = ws;  ws += (size_t)N * 4;
    float* adst = ws;  ws += (size_t)N * 4;
    float* gate = ws;  ws += N;
    int* deg    = (int*)ws; ws += N;
    int* cursor = (int*)ws; ws += N;
    int* rowptr = (int*)ws; ws += (N + 1);
    int* csrc   = (int*)ws; ws += Etot;
    int* gstart = (int*)ws; ws += (G + 1);
    int* bsum   = (int*)ws; ws += 256;
    int* bpref  = (int*)ws; ws += 256;
    __bf16* x4 = x1;

    const int SB = (N + SCB - 1) / SCB;

    hipLaunchKernelGGL(conv_pad_kernel, dim3(512), dim3(256), 0, stream, x, xb, N, IN, INp);
    hipLaunchKernelGGL(wtrans_all_kernel, dim3(896), dim3(256), 0, stream,
                       W[0], W[1], W[2], W[3], wt1, wt2, wt3, wt4, IN);

    hipMemsetAsync(deg, 0, (size_t)N * 4, stream);
    hipLaunchKernelGGL(deg_count_kernel, dim3((Etot + 255) / 256), dim3(256), 0, stream,
                       ei, deg, E, Etot);
    hipLaunchKernelGGL(scan1_kernel, dim3(SB), dim3(256), 0, stream, deg, bsum, N);
    hipLaunchKernelGGL(scan2_kernel, dim3(1), dim3(256), 0, stream, bsum, bpref, SB,
                       &rowptr[N]);
    hipLaunchKernelGGL(scan3_kernel, dim3(SB), dim3(256), 0, stream, deg, bpref,
                       rowptr, cursor, N);
    hipLaunchKernelGGL(scatter_kernel, dim3((Etot + 255) / 256), dim3(256), 0, stream,
                       ei, cursor, csrc, E, Etot);
    hipLaunchKernelGGL(gstart_kernel, dim3((N + 255) / 256), dim3(256), 0, stream,
                       batch, gstart, N, G);

    const int grid256 = (N + 63) / 64;
    const int grid128 = (N + 127) / 128;
    const int gatgrid = (N + 3) / 4;

    hipLaunchKernelGGL((gemm_fused<256, 4, false>), dim3(grid256), dim3(256), 0, stream,
                       xb, nullptr, wt1, avs[0], avd[0], h8, hsc, asrc, adst, N, INp);
    hipLaunchKernelGGL((gat_agg<4, 64, false>), dim3(gatgrid), dim3(256), 0, stream,
                       rowptr, csrc, h8, hsc, asrc, adst, bi[0], ga[0], be[0], mu[0], va[0],
                       x1, nullptr, nullptr, nullptr, nullptr, nullptr, N);
    hipLaunchKernelGGL((gemm_fused<256, 4, false>), dim3(grid256), dim3(256), 0, stream,
                       x1, nullptr, wt2, avs[1], avd[1], h8, hsc, asrc, adst, N, 256);
    hipLaunchKernelGGL((gat_agg<4, 64, false>), dim3(gatgrid), dim3(256), 0, stream,
                       rowptr, csrc, h8, hsc, asrc, adst, bi[1], ga[1], be[1], mu[1], va[1],
                       x2, nullptr, nullptr, nullptr, nullptr, nullptr, N);
    hipLaunchKernelGGL((gemm_fused<256, 4, true>), dim3(grid256), dim3(256), 0, stream,
                       x1, x2, wt3, avs[2], avd[2], h8, hsc, asrc, adst, N, 256);
    hipLaunchKernelGGL((gat_agg<4, 64, false>), dim3(gatgrid), dim3(256), 0, stream,
                       rowptr, csrc, h8, hsc, asrc, adst, bi[2], ga[2], be[2], mu[2], va[2],
                       x3, nullptr, nullptr, nullptr, nullptr, nullptr, N);
    hipLaunchKernelGGL((gemm_fused<128, 1, false>), dim3(grid128), dim3(256), 0, stream,
                       x3, nullptr, wt4, avs[3], avd[3], h8, hsc, asrc, adst, N, 256);
    hipLaunchKernelGGL((gat_agg<1, 128, true>), dim3(gatgrid), dim3(256), 0, stream,
                       rowptr, csrc, h8, hsc, asrc, adst, bi[3], ga[3], be[3], mu[3], va[3],
                       x4, pw1, pb1, pw2, pb2, gate, N);

    hipLaunchKernelGGL(pool_kernel, dim3(G), dim3(128), 0, stream, x4, gate, gstart, out);
    hipLaunchKernelGGL(gfeat_kernel, dim3(G), dim3(64), 0, stream, gfeat, gw, gb, out);
}

// Round 11
// 535.205 us; speedup vs baseline: 1.0838x; 1.0191x over previous
//
#include <hip/hip_runtime.h>
#include <cstdint>
#include <cstddef>

#define NEG_SLOPE 0.2f
#define BN_EPS 1e-5f

typedef __bf16 bf16x8 __attribute__((ext_vector_type(8)));
typedef float  f32x4  __attribute__((ext_vector_type(4)));

// single-instruction byte->float (v_cvt_f32_ubyteN)
__device__ __forceinline__ float ub0(unsigned u) { return (float)(u & 0xffu); }
__device__ __forceinline__ float ub1(unsigned u) { return (float)((u >> 8) & 0xffu); }
__device__ __forceinline__ float ub2(unsigned u) { return (float)((u >> 16) & 0xffu); }
__device__ __forceinline__ float ub3(unsigned u) { return (float)((u >> 24) & 0xffu); }

// ---------- prep: x fp32 [N][K] -> bf16 [N][Kpad] zero-padded ----------
__global__ void conv_pad_kernel(const float* __restrict__ x, __bf16* __restrict__ xb,
                                int N, int K, int Kpad) {
    int i = blockIdx.x * blockDim.x + threadIdx.x;
    int total = N * Kpad;
    for (; i < total; i += gridDim.x * blockDim.x) {
        int n = i / Kpad, k = i - n * Kpad;
        xb[i] = (k < K) ? (__bf16)x[(size_t)n * K + k] : (__bf16)0.f;
    }
}

// ---------- prep: all weight transposes (W1..W4 + pw1) in one launch ----------
__global__ void wtrans_all_kernel(const float* __restrict__ W1, const float* __restrict__ W2,
                                  const float* __restrict__ W3, const float* __restrict__ W4,
                                  const float* __restrict__ PW1,
                                  __bf16* __restrict__ wt1, __bf16* __restrict__ wt2,
                                  __bf16* __restrict__ wt3, __bf16* __restrict__ wt4,
                                  __bf16* __restrict__ pw1t, int IN) {
    int b = blockIdx.x;
    const float* W; __bf16* WT; int K, D, Kpad, col;
    if (b < 256)      { W = W1;  WT = wt1;  K = IN;  D = 256; Kpad = 64;  col = b; }
    else if (b < 512) { W = W2;  WT = wt2;  K = 256; D = 256; Kpad = 256; col = b - 256; }
    else if (b < 768) { W = W3;  WT = wt3;  K = 256; D = 256; Kpad = 256; col = b - 512; }
    else if (b < 896) { W = W4;  WT = wt4;  K = 256; D = 128; Kpad = 256; col = b - 768; }
    else              { W = PW1; WT = pw1t; K = 128; D = 32;  Kpad = 128; col = b - 896; }
    for (int k = threadIdx.x; k < Kpad; k += blockDim.x)
        WT[(size_t)col * Kpad + k] = (k < K) ? (__bf16)W[(size_t)k * D + col] : (__bf16)0.f;
}

// ================= LDS-free MFMA GEMM strip + fused alpha + u8-quant H ====
// H stored excess-128 uint8 with per-row scale hscale[row] = rowmax/127.
template<int DCOLS, int HEADS, bool HAS_A2>
__global__ __launch_bounds__(256) void gemm_fused(
    const __bf16* __restrict__ A, const __bf16* __restrict__ A2,
    const __bf16* __restrict__ WT,
    const float* __restrict__ asv, const float* __restrict__ adv,
    uint8_t* __restrict__ H8, float* __restrict__ hscale,
    float* __restrict__ alpha_s, float* __restrict__ alpha_d,
    int M, int K) {
    constexpr int RB = (DCOLS == 256) ? 64 : 128;
    constexpr int NW = (DCOLS == 256) ? 4 : 2;
    const int w    = threadIdx.x >> 6;
    const int lane = threadIdx.x & 63;
    const int l16  = lane & 15, hi4 = lane >> 4;
    const int rg    = (DCOLS == 256) ? 0 : (w >> 1);
    const int ct    = (DCOLS == 256) ? w : (w & 1);
    const int col0w = ct * 64;
    const int rbase = rg * 64;
    const int n0 = blockIdx.x * RB;
    const int lk = hi4 * 8;

    f32x4 acc[4][4] = {};
    int arow[4];
    #pragma unroll
    for (int i = 0; i < 4; ++i) {
        int r = n0 + rbase + i * 16 + l16;
        arow[i] = (r < M) ? r : (M - 1);
    }

    for (int k0 = 0; k0 < K; k0 += 32) {
        bf16x8 af[4], bfr[4];
        #pragma unroll
        for (int i = 0; i < 4; ++i) {
            bf16x8 v = *(const bf16x8*)&A[(size_t)arow[i] * K + k0 + lk];
            if (HAS_A2) {
                bf16x8 v2 = *(const bf16x8*)&A2[(size_t)arow[i] * K + k0 + lk];
                #pragma unroll
                for (int j = 0; j < 8; ++j) v[j] = (__bf16)((float)v[j] + (float)v2[j]);
            }
            af[i] = v;
        }
        #pragma unroll
        for (int j = 0; j < 4; ++j)
            bfr[j] = *(const bf16x8*)&WT[(size_t)(col0w + j * 16 + l16) * K + k0 + lk];
        #pragma unroll
        for (int i = 0; i < 4; ++i)
            #pragma unroll
            for (int j = 0; j < 4; ++j)
                acc[i][j] = __builtin_amdgcn_mfma_f32_16x16x32_bf16(
                    af[i], bfr[j], acc[i][j], 0, 0, 0);
    }

    // ---- fused alpha ----
    float asc[4], adc[4];
    #pragma unroll
    for (int j = 0; j < 4; ++j) {
        int c = col0w + j * 16 + l16;
        asc[j] = asv[c]; adc[j] = adv[c];
    }
    __shared__ float as_l[128][2], ad_l[128][2];
    __shared__ float rmaxl[RB][NW];
    #pragma unroll
    for (int i = 0; i < 4; ++i)
        #pragma unroll
        for (int q = 0; q < 4; ++q) {
            float ps = 0.f, pd = 0.f;
            #pragma unroll
            for (int j = 0; j < 4; ++j) {
                float v = acc[i][j][q];
                ps = fmaf(v, asc[j], ps);
                pd = fmaf(v, adc[j], pd);
            }
            #pragma unroll
            for (int o = 1; o < 16; o <<= 1) {
                ps += __shfl_xor(ps, o, 64);
                pd += __shfl_xor(pd, o, 64);
            }
            int rl = rbase + i * 16 + hi4 * 4 + q;
            if constexpr (DCOLS == 256) {
                int row = n0 + rl;
                if (l16 == 0 && row < M) {
                    alpha_s[row * HEADS + w] = ps;
                    alpha_d[row * HEADS + w] = pd;
                }
            } else {
                if (l16 == 0) { as_l[rl][ct] = ps; ad_l[rl][ct] = pd; }
            }
        }

    // ---- per-row max(|acc|) for quantization ----
    float rm[4][4];
    #pragma unroll
    for (int i = 0; i < 4; ++i)
        #pragma unroll
        for (int q = 0; q < 4; ++q) {
            float m = fabsf(acc[i][0][q]);
            #pragma unroll
            for (int j = 1; j < 4; ++j) m = fmaxf(m, fabsf(acc[i][j][q]));
            rm[i][q] = m;
        }
    #pragma unroll
    for (int o = 1; o < 16; o <<= 1)
        #pragma unroll
        for (int i = 0; i < 4; ++i)
            #pragma unroll
            for (int q = 0; q < 4; ++q)
                rm[i][q] = fmaxf(rm[i][q], __shfl_xor(rm[i][q], o, 64));
    if (l16 == 0) {
        #pragma unroll
        for (int i = 0; i < 4; ++i)
            #pragma unroll
            for (int q = 0; q < 4; ++q)
                rmaxl[rbase + i * 16 + hi4 * 4 + q][(DCOLS == 256) ? w : ct] = rm[i][q];
    }
    __syncthreads();

    if constexpr (DCOLS == 128) {
        int t = threadIdx.x;
        if (t < 128) {
            int row = n0 + t;
            if (row < M) {
                alpha_s[row] = as_l[t][0] + as_l[t][1];
                alpha_d[row] = ad_l[t][0] + ad_l[t][1];
            }
        }
    }

    // ---- quantize (excess-128) + store ----
    #pragma unroll
    for (int i = 0; i < 4; ++i)
        #pragma unroll
        for (int q = 0; q < 4; ++q) {
            int rl = rbase + i * 16 + hi4 * 4 + q;
            float m4 = rmaxl[rl][0];
            #pragma unroll
            for (int k = 1; k < NW; ++k) m4 = fmaxf(m4, rmaxl[rl][k]);
            float qinv = (m4 > 1e-30f) ? 127.f / m4 : 0.f;
            int row = n0 + rl;
            if (row < M) {
                if (l16 == 0 && ct == 0 && (DCOLS == 128 || w == 0))
                    hscale[row] = m4 * (1.f / 127.f);
                #pragma unroll
                for (int j = 0; j < 4; ++j)
                    H8[(size_t)row * DCOLS + col0w + j * 16 + l16] =
                        (uint8_t)((int)rintf(acc[i][j][q] * qinv) + 128);
            }
        }
}

// ================= CSR build (once per call) =================
__global__ void deg_count_kernel(const int* __restrict__ ei, int* __restrict__ deg,
                                 int E, int Etot) {
    int e = blockIdx.x * blockDim.x + threadIdx.x;
    if (e >= Etot) return;
    int d = (e < E) ? ei[E + e] : e - E;
    atomicAdd(&deg[d], 1);
}

#define SCB 4096
__global__ __launch_bounds__(256) void scan1_kernel(const int* __restrict__ deg,
                                                    int* __restrict__ bsum, int N) {
    __shared__ int ts[256];
    const int t = threadIdx.x;
    const int base = blockIdx.x * SCB + t * 16;
    int s = 0;
    #pragma unroll
    for (int i = 0; i < 16; ++i) {
        int idx = base + i;
        if (idx < N) s += deg[idx];
    }
    ts[t] = s;
    __syncthreads();
    for (int off = 128; off > 0; off >>= 1) {
        if (t < off) ts[t] += ts[t + off];
        __syncthreads();
    }
    if (t == 0) bsum[blockIdx.x] = ts[0];
}

__global__ __launch_bounds__(256) void scan2_kernel(const int* __restrict__ bsum,
                                                    int* __restrict__ bpref, int B,
                                                    int* __restrict__ rowptrN) {
    __shared__ int sm[256];
    const int t = threadIdx.x;
    int v = (t < B) ? bsum[t] : 0;
    sm[t] = v;
    __syncthreads();
    for (int off = 1; off < 256; off <<= 1) {
        int u = (t >= off) ? sm[t - off] : 0;
        __syncthreads();
        sm[t] += u;
        __syncthreads();
    }
    if (t < B) bpref[t] = sm[t] - v;
    if (t == 255) *rowptrN = sm[255];
}

__global__ __launch_bounds__(256) void scan3_kernel(const int* __restrict__ deg,
                                                    const int* __restrict__ bpref,
                                                    int* __restrict__ rowptr,
                                                    int* __restrict__ cursor, int N) {
    __shared__ int ts[256];
    const int t = threadIdx.x;
    const int base = blockIdx.x * SCB + t * 16;
    int d[16];
    int s = 0;
    #pragma unroll
    for (int i = 0; i < 16; ++i) {
        int idx = base + i;
        d[i] = (idx < N) ? deg[idx] : 0;
        s += d[i];
    }
    ts[t] = s;
    __syncthreads();
    for (int off = 1; off < 256; off <<= 1) {
        int u = (t >= off) ? ts[t - off] : 0;
        __syncthreads();
        ts[t] += u;
        __syncthreads();
    }
    int run = bpref[blockIdx.x] + ts[t] - s;
    #pragma unroll
    for (int i = 0; i < 16; ++i) {
        int idx = base + i;
        if (idx < N) { rowptr[idx] = run; cursor[idx] = run; run += d[i]; }
    }
}

__global__ void scatter_kernel(const int* __restrict__ ei, int* __restrict__ cursor,
                               int* __restrict__ csrc, int E, int Etot) {
    int e = blockIdx.x * blockDim.x + threadIdx.x;
    if (e >= Etot) return;
    int s, d;
    if (e < E) { s = ei[e]; d = ei[E + e]; } else { s = d = e - E; }
    int pos = atomicAdd(&cursor[d], 1);
    csrc[pos] = s;
}

__global__ void gstart_kernel(const int* __restrict__ batch, int* __restrict__ gstart,
                              int N, int G) {
    int n = blockIdx.x * blockDim.x + threadIdx.x;
    if (n >= N) return;
    int b = batch[n];
    if (n == 0) { for (int g = 0; g <= b; ++g) gstart[g] = 0; }
    else {
        int bp = batch[n - 1];
        for (int g = bp + 1; g <= b; ++g) gstart[g] = n;
    }
    if (n == N - 1) { for (int g = b + 1; g <= G; ++g) gstart[g] = N; }
}

// ============ wave-per-node GAT edge phase, excess-128 uint8 gather ============
template<int HEADS, int C>
__global__ __launch_bounds__(256) void gat_agg(
    const int* __restrict__ rowptr, const int* __restrict__ csrc,
    const uint8_t* __restrict__ hf, const float* __restrict__ hscale,
    const float* __restrict__ asrc, const float* __restrict__ adst,
    const float* __restrict__ bias, const float* __restrict__ gamma,
    const float* __restrict__ beta, const float* __restrict__ mean,
    const float* __restrict__ var,
    __bf16* __restrict__ out, int N) {
    constexpr int D   = HEADS * C;
    constexpr int LPE = D / 8;      // lanes per edge (8 cols x 1B)
    constexpr int EPW = 64 / LPE;   // edges in flight per wave-step

    const int wid  = threadIdx.x >> 6;
    const int lane = threadIdx.x & 63;
    const int node = blockIdx.x * 4 + wid;

    __shared__ int   soff[4][64];
    __shared__ float pal[4][64][HEADS];

    if (node >= N) return;

    const int beg = rowptr[node], end = rowptr[node + 1];
    const int deg = end - beg;
    const int grp = lane / LPE;
    const int c0  = (lane % LPE) * 8;
    const int hd  = c0 / C;
    const uint8_t* hb = hf + c0;

    float ad[HEADS];
    #pragma unroll
    for (int h = 0; h < HEADS; ++h) ad[h] = adst[node * HEADS + h];

    float acc8[8] = {};
    float psum = 0.f;   // sum of folded alpha weights over my edge subset

    auto fmau8 = [&](uint2 v, float q) {
        acc8[0] = fmaf(ub0(v.x), q, acc8[0]);
        acc8[1] = fmaf(ub1(v.x), q, acc8[1]);
        acc8[2] = fmaf(ub2(v.x), q, acc8[2]);
        acc8[3] = fmaf(ub3(v.x), q, acc8[3]);
        acc8[4] = fmaf(ub0(v.y), q, acc8[4]);
        acc8[5] = fmaf(ub1(v.y), q, acc8[5]);
        acc8[6] = fmaf(ub2(v.y), q, acc8[6]);
        acc8[7] = fmaf(ub3(v.y), q, acc8[7]);
    };

    auto agg_chunk = [&](int cnt) {
        int e = 0;
        for (; e + 4 * EPW <= cnt; e += 4 * EPW) {
            int o0 = soff[wid][e + 0 * EPW + grp];
            int o1 = soff[wid][e + 1 * EPW + grp];
            int o2 = soff[wid][e + 2 * EPW + grp];
            int o3 = soff[wid][e + 3 * EPW + grp];
            float q0 = pal[wid][e + 0 * EPW + grp][hd];
            float q1 = pal[wid][e + 1 * EPW + grp][hd];
            float q2 = pal[wid][e + 2 * EPW + grp][hd];
            float q3 = pal[wid][e + 3 * EPW + grp][hd];
            uint2 v0 = *(const uint2*)(hb + o0);
            uint2 v1 = *(const uint2*)(hb + o1);
            uint2 v2 = *(const uint2*)(hb + o2);
            uint2 v3 = *(const uint2*)(hb + o3);
            psum += (q0 + q1) + (q2 + q3);
            fmau8(v0, q0); fmau8(v1, q1); fmau8(v2, q2); fmau8(v3, q3);
        }
        for (; e + EPW <= cnt; e += EPW) {
            int o0 = soff[wid][e + grp];
            float q0 = pal[wid][e + grp][hd];
            uint2 v0 = *(const uint2*)(hb + o0);
            psum += q0;
            fmau8(v0, q0);
        }
        if (e < cnt) {
            int r = cnt - e;
            int o0 = soff[wid][(grp < r) ? e + grp : e];
            float q0 = (grp < r) ? pal[wid][e + grp][hd] : 0.f;
            uint2 v0 = *(const uint2*)(hb + o0);
            psum += q0;
            fmau8(v0, q0);
        }
    };

    if (deg <= 64) {
        const bool act = lane < deg;
        int msrc = act ? csrc[beg + lane] : 0;
        float hs = act ? hscale[msrc] : 0.f;
        float lv[HEADS];
        if constexpr (HEADS == 4) {
            float4 a4 = ((const float4*)asrc)[msrc];
            lv[0] = a4.x; lv[1] = a4.y; lv[2] = a4.z; lv[3] = a4.w;
        } else {
            lv[0] = asrc[msrc];
        }
        float p[HEADS];
        #pragma unroll
        for (int h = 0; h < HEADS; ++h) {
            float v;
            if (act) { v = lv[h] + ad[h]; v = v > 0.f ? v : NEG_SLOPE * v; }
            else v = -INFINITY;
            float mx = v;
            #pragma unroll
            for (int o = 1; o < 64; o <<= 1) mx = fmaxf(mx, __shfl_xor(mx, o, 64));
            float pe = act ? __expf(v - mx) : 0.f;
            float ps = pe;
            #pragma unroll
            for (int o = 1; o < 64; o <<= 1) ps += __shfl_xor(ps, o, 64);
            p[h] = pe * (1.f / (ps + 1e-16f)) * hs;   // fold src row scale
        }
        soff[wid][lane] = msrc * D;
        if constexpr (HEADS == 4)
            *(float4*)&pal[wid][lane][0] = make_float4(p[0], p[1], p[2], p[3]);
        else
            pal[wid][lane][0] = p[0];
        asm volatile("s_waitcnt lgkmcnt(0)" ::: "memory");
        agg_chunk(deg);
    } else {
        float mx[HEADS], sm[HEADS], inv[HEADS];
        #pragma unroll
        for (int h = 0; h < HEADS; ++h) mx[h] = -INFINITY;
        for (int j = beg + lane; j < end; j += 64) {
            int s = csrc[j];
            #pragma unroll
            for (int h = 0; h < HEADS; ++h) {
                float v = asrc[s * HEADS + h] + ad[h];
                v = v > 0.f ? v : NEG_SLOPE * v;
                mx[h] = fmaxf(mx[h], v);
            }
        }
        #pragma unroll
        for (int h = 0; h < HEADS; ++h) {
            #pragma unroll
            for (int o = 1; o < 64; o <<= 1) mx[h] = fmaxf(mx[h], __shfl_xor(mx[h], o, 64));
            sm[h] = 0.f;
        }
        for (int j = beg + lane; j < end; j += 64) {
            int s = csrc[j];
            #pragma unroll
            for (int h = 0; h < HEADS; ++h) {
                float v = asrc[s * HEADS + h] + ad[h];
                v = v > 0.f ? v : NEG_SLOPE * v;
                sm[h] += __expf(v - mx[h]);
            }
        }
        #pragma unroll
        for (int h = 0; h < HEADS; ++h) {
            #pragma unroll
            for (int o = 1; o < 64; o <<= 1) sm[h] += __shfl_xor(sm[h], o, 64);
            inv[h] = 1.f / (sm[h] + 1e-16f);
        }
        for (int base2 = beg; base2 < end; base2 += 64) {
            int ne = min(64, end - base2);
            bool act2 = lane < ne;
            int msrc = csrc[base2 + (act2 ? lane : 0)];
            float hs = act2 ? hscale[msrc] : 0.f;
            soff[wid][lane] = msrc * D;
            #pragma unroll
            for (int h = 0; h < HEADS; ++h) {
                float pv = 0.f;
                if (act2) {
                    float v = asrc[msrc * HEADS + h] + ad[h];
                    v = v > 0.f ? v : NEG_SLOPE * v;
                    pv = __expf(v - mx[h]) * inv[h] * hs;
                }
                pal[wid][lane][h] = pv;
            }
            asm volatile("s_waitcnt lgkmcnt(0)" ::: "memory");
            agg_chunk(ne);
            asm volatile("s_waitcnt lgkmcnt(0)" ::: "memory");
        }
    }

    // ---- merge edge-group partials (psum merges through the same tree) ----
    #pragma unroll
    for (int o = LPE; o < 64; o <<= 1) {
        #pragma unroll
        for (int i = 0; i < 8; ++i)
            acc8[i] += __shfl_xor(acc8[i], o, 64);
        psum += __shfl_xor(psum, o, 64);
    }

    // ---- epilogue: excess-128 correction + bias + BN + ReLU -> bf16 ----
    if (lane < LPE) {
        bf16x8 ov;
        #pragma unroll
        for (int i = 0; i < 8; ++i) {
            int c = c0 + i;
            float v = acc8[i] - 128.f * psum + bias[c];
            v = (v - mean[c]) * rsqrtf(var[c] + BN_EPS) * gamma[c] + beta[c];
            v = fmaxf(v, 0.f);
            ov[i] = (__bf16)v;
        }
        *(bf16x8*)&out[(size_t)node * D + c0] = ov;
    }
}

// ---------- gate MLP via MFMA: gate = relu(x4@pw1+pb1)@pw2+pb2 ----------
// wave = 16 nodes; pw1t bf16 [32][128].
__global__ __launch_bounds__(256) void gate_gemm_kernel(
    const __bf16* __restrict__ x4, const __bf16* __restrict__ pw1t,
    const float* __restrict__ pb1, const float* __restrict__ pw2,
    const float* __restrict__ pb2, float* __restrict__ gate, int N) {
    const int w    = threadIdx.x >> 6;
    const int lane = threadIdx.x & 63;
    const int l16  = lane & 15, hi4 = lane >> 4;
    const int n0 = (blockIdx.x * 4 + w) * 16;
    if (n0 >= N) return;
    const int arow = min(n0 + l16, N - 1);
    f32x4 acc[2] = {};
    #pragma unroll
    for (int k0 = 0; k0 < 128; k0 += 32) {
        bf16x8 af = *(const bf16x8*)&x4[(size_t)arow * 128 + k0 + hi4 * 8];
        bf16x8 b0 = *(const bf16x8*)&pw1t[(size_t)l16 * 128 + k0 + hi4 * 8];
        bf16x8 b1 = *(const bf16x8*)&pw1t[(size_t)(16 + l16) * 128 + k0 + hi4 * 8];
        acc[0] = __builtin_amdgcn_mfma_f32_16x16x32_bf16(af, b0, acc[0], 0, 0, 0);
        acc[1] = __builtin_amdgcn_mfma_f32_16x16x32_bf16(af, b1, acc[1], 0, 0, 0);
    }
    // C layout: col = l16 (+16 for frag1), row = hi4*4+q
    float pb1a = pb1[l16], pb1b = pb1[16 + l16];
    float w2a = pw2[l16], w2b = pw2[16 + l16];
    #pragma unroll
    for (int q = 0; q < 4; ++q) {
        float g = fmaxf(acc[0][q] + pb1a, 0.f) * w2a +
                  fmaxf(acc[1][q] + pb1b, 0.f) * w2b;
        #pragma unroll
        for (int o = 1; o < 16; o <<= 1) g += __shfl_xor(g, o, 64);
        int row = n0 + hi4 * 4 + q;
        if (l16 == 0 && row < N) gate[row] = g + pb2[0];
    }
}

// ---------- block-per-graph pooling ----------
__global__ __launch_bounds__(128) void pool_kernel(
    const __bf16* __restrict__ x4, const float* __restrict__ gate,
    const int* __restrict__ gstart, float* __restrict__ out) {
    const int g = blockIdx.x;
    const int t = threadIdx.x;
    const int beg = gstart[g], end = gstart[g + 1];
    __shared__ float red[128];
    __shared__ float wbuf[128];
    float m = -INFINITY;
    for (int n = beg + t; n < end; n += 128) m = fmaxf(m, gate[n]);
    red[t] = m; __syncthreads();
    for (int off = 64; off > 0; off >>= 1) {
        if (t < off) red[t] = fmaxf(red[t], red[t + off]);
        __syncthreads();
    }
    m = red[0]; __syncthreads();
    float s = 0.f;
    for (int n = beg + t; n < end; n += 128) s += expf(gate[n] - m);
    red[t] = s; __syncthreads();
    for (int off = 64; off > 0; off >>= 1) {
        if (t < off) red[t] += red[t + off];
        __syncthreads();
    }
    const float inv = 1.f / (red[0] + 1e-16f);
    __syncthreads();
    float acc = 0.f;
    for (int base = beg; base < end; base += 128) {
        int ne = min(128, end - base);
        if (t < ne) wbuf[t] = expf(gate[base + t] - m) * inv;
        __syncthreads();
        for (int i = 0; i < ne; ++i)
            acc = fmaf(wbuf[i], (float)x4[(size_t)(base + i) * 128 + t], acc);
        __syncthreads();
    }
    out[(size_t)g * 160 + t] = acc;
}

// ---------- global-feature MLP into d_out[:, 128:160] ----------
__global__ void gfeat_kernel(const float* __restrict__ gfeat,
                             const float* __restrict__ gw, const float* __restrict__ gb,
                             float* __restrict__ out) {
    const int g = blockIdx.x;
    const int k = threadIdx.x;
    if (k < 32) {
        float t = gb[k];
        #pragma unroll
        for (int j = 0; j < 7; ++j) t = fmaf(gfeat[g * 7 + j], gw[j * 32 + k], t);
        out[(size_t)g * 160 + 128 + k] = fmaxf(t, 0.f);
    }
}

// ==========================================================================
extern "C" void kernel_launch(void* const* d_in, const int* in_sizes, int n_in,
                              void* d_out, int out_size, void* d_ws, size_t ws_size,
                              hipStream_t stream) {
    const float* x      = (const float*)d_in[0];
    const int*   ei     = (const int*)  d_in[1];
    const int*   batch  = (const int*)  d_in[2];
    const float* gfeat  = (const float*)d_in[3];

    const int N    = in_sizes[2];
    const int E    = in_sizes[1] / 2;
    const int G    = in_sizes[3] / 7;
    const int IN   = in_sizes[0] / N;
    const int Etot = E + N;
    const int INp  = 64;

    const float* W[4];  const float* avs[4]; const float* avd[4]; const float* bi[4];
    const float* ga[4]; const float* be[4];  const float* mu[4];  const float* va[4];
    for (int l = 0; l < 4; ++l) {
        int o = 4 + 8 * l;
        W[l]   = (const float*)d_in[o + 0];
        avs[l] = (const float*)d_in[o + 1];
        avd[l] = (const float*)d_in[o + 2];
        bi[l]  = (const float*)d_in[o + 3];
        ga[l]  = (const float*)d_in[o + 4];
        be[l]  = (const float*)d_in[o + 5];
        mu[l]  = (const float*)d_in[o + 6];
        va[l]  = (const float*)d_in[o + 7];
    }
    const float* pw1 = (const float*)d_in[36];
    const float* pb1 = (const float*)d_in[37];
    const float* pw2 = (const float*)d_in[38];
    const float* pb2 = (const float*)d_in[39];
    const float* gw  = (const float*)d_in[40];
    const float* gb  = (const float*)d_in[41];

    float* out = (float*)d_out;

    float* ws = (float*)d_ws;
    __bf16* xb = (__bf16*)ws; ws += (size_t)N * 32;
    uint8_t* h8 = (uint8_t*)ws; ws += (size_t)N * 64;   // N x 256 u8
    float* hsc = ws;  ws += N;
    __bf16* x1 = (__bf16*)ws; ws += (size_t)N * 128;
    __bf16* x2 = (__bf16*)ws; ws += (size_t)N * 128;
    __bf16* x3 = (__bf16*)ws; ws += (size_t)N * 128;
    __bf16* wt1 = (__bf16*)ws; ws += 256 * 64 / 2;
    __bf16* wt2 = (__bf16*)ws; ws += 256 * 256 / 2;
    __bf16* wt3 = (__bf16*)ws; ws += 256 * 256 / 2;
    __bf16* wt4 = (__bf16*)ws; ws += 128 * 256 / 2;
    __bf16* pw1t = (__bf16*)ws; ws += 32 * 128 / 2;
    float* asrc = ws;  ws += (size_t)N * 4;
    float* adst = ws;  ws += (size_t)N * 4;
    float* gate = ws;  ws += N;
    int* deg    = (int*)ws; ws += N;
    int* cursor = (int*)ws; ws += N;
    int* rowptr = (int*)ws; ws += (N + 1);
    int* csrc   = (int*)ws; ws += Etot;
    int* gstart = (int*)ws; ws += (G + 1);
    int* bsum   = (int*)ws; ws += 256;
    int* bpref  = (int*)ws; ws += 256;
    __bf16* x4 = x1;

    const int SB = (N + SCB - 1) / SCB;

    hipLaunchKernelGGL(conv_pad_kernel, dim3(512), dim3(256), 0, stream, x, xb, N, IN, INp);
    hipLaunchKernelGGL(wtrans_all_kernel, dim3(928), dim3(256), 0, stream,
                       W[0], W[1], W[2], W[3], pw1, wt1, wt2, wt3, wt4, pw1t, IN);

    hipMemsetAsync(deg, 0, (size_t)N * 4, stream);
    hipLaunchKernelGGL(deg_count_kernel, dim3((Etot + 255) / 256), dim3(256), 0, stream,
                       ei, deg, E, Etot);
    hipLaunchKernelGGL(scan1_kernel, dim3(SB), dim3(256), 0, stream, deg, bsum, N);
    hipLaunchKernelGGL(scan2_kernel, dim3(1), dim3(256), 0, stream, bsum, bpref, SB,
                       &rowptr[N]);
    hipLaunchKernelGGL(scan3_kernel, dim3(SB), dim3(256), 0, stream, deg, bpref,
                       rowptr, cursor, N);
    hipLaunchKernelGGL(scatter_kernel, dim3((Etot + 255) / 256), dim3(256), 0, stream,
                       ei, cursor, csrc, E, Etot);
    hipLaunchKernelGGL(gstart_kernel, dim3((N + 255) / 256), dim3(256), 0, stream,
                       batch, gstart, N, G);

    const int grid256 = (N + 63) / 64;
    const int grid128 = (N + 127) / 128;
    const int gatgrid = (N + 3) / 4;

    hipLaunchKernelGGL((gemm_fused<256, 4, false>), dim3(grid256), dim3(256), 0, stream,
                       xb, nullptr, wt1, avs[0], avd[0], h8, hsc, asrc, adst, N, INp);
    hipLaunchKernelGGL((gat_agg<4, 64>), dim3(gatgrid), dim3(256), 0, stream,
                       rowptr, csrc, h8, hsc, asrc, adst, bi[0], ga[0], be[0], mu[0], va[0],
                       x1, N);
    hipLaunchKernelGGL((gemm_fused<256, 4, false>), dim3(grid256), dim3(256), 0, stream,
                       x1, nullptr, wt2, avs[1], avd[1], h8, hsc, asrc, adst, N, 256);
    hipLaunchKernelGGL((gat_agg<4, 64>), dim3(gatgrid), dim3(256), 0, stream,
                       rowptr, csrc, h8, hsc, asrc, adst, bi[1], ga[1], be[1], mu[1], va[1],
                       x2, N);
    hipLaunchKernelGGL((gemm_fused<256, 4, true>), dim3(grid256), dim3(256), 0, stream,
                       x1, x2, wt3, avs[2], avd[2], h8, hsc, asrc, adst, N, 256);
    hipLaunchKernelGGL((gat_agg<4, 64>), dim3(gatgrid), dim3(256), 0, stream,
                       rowptr, csrc, h8, hsc, asrc, adst, bi[2], ga[2], be[2], mu[2], va[2],
                       x3, N);
    hipLaunchKernelGGL((gemm_fused<128, 1, false>), dim3(grid128), dim3(256), 0, stream,
                       x3, nullptr, wt4, avs[3], avd[3], h8, hsc, asrc, adst, N, 256);
    hipLaunchKernelGGL((gat_agg<1, 128>), dim3(gatgrid), dim3(256), 0, stream,
                       rowptr, csrc, h8, hsc, asrc, adst, bi[3], ga[3], be[3], mu[3], va[3],
                       x4, N);

    hipLaunchKernelGGL(gate_gemm_kernel, dim3((N + 63) / 64), dim3(256), 0, stream,
                       x4, pw1t, pb1, pw2, pb2, gate, N);
    hipLaunchKernelGGL(pool_kernel, dim3(G), dim3(128), 0, stream, x4, gate, gstart, out);
    hipLaunchKernelGGL(gfeat_kernel, dim3(G), dim3(64), 0, stream, gfeat, gw, gb, out);
}

// Round 13
// 493.946 us; speedup vs baseline: 1.1744x; 1.0835x over previous
//
#include <hip/hip_runtime.h>
#include <cstdint>
#include <cstddef>

#define NEG_SLOPE 0.2f
#define BN_EPS 1e-5f

typedef __bf16 bf16x8 __attribute__((ext_vector_type(8)));
typedef float  f32x4  __attribute__((ext_vector_type(4)));

// single-instruction byte->float (v_cvt_f32_ubyteN)
__device__ __forceinline__ float ub0(unsigned u) { return (float)(u & 0xffu); }
__device__ __forceinline__ float ub1(unsigned u) { return (float)((u >> 8) & 0xffu); }
__device__ __forceinline__ float ub2(unsigned u) { return (float)((u >> 16) & 0xffu); }
__device__ __forceinline__ float ub3(unsigned u) { return (float)((u >> 24) & 0xffu); }

// ---------- prep: x fp32 [N][K] -> bf16 [N][Kpad] zero-padded ----------
__global__ void conv_pad_kernel(const float* __restrict__ x, __bf16* __restrict__ xb,
                                int N, int K, int Kpad) {
    int i = blockIdx.x * blockDim.x + threadIdx.x;
    int total = N * Kpad;
    for (; i < total; i += gridDim.x * blockDim.x) {
        int n = i / Kpad, k = i - n * Kpad;
        xb[i] = (k < K) ? (__bf16)x[(size_t)n * K + k] : (__bf16)0.f;
    }
}

// ---------- prep: weight transposes + BN coefficient fold, one launch ----------
// blocks 0..927: W1..W4 + pw1 transpose. blocks 928..931: per-layer BN fold:
//   S = gamma * rsqrt(var+eps); T = (bias-mean)*S + beta.
// BN pointers passed directly as kernel args (NO host memcpy: graph-capture safe).
__global__ void prep_all_kernel(
    const float* __restrict__ W1, const float* __restrict__ W2,
    const float* __restrict__ W3, const float* __restrict__ W4,
    const float* __restrict__ PW1,
    __bf16* __restrict__ wt1, __bf16* __restrict__ wt2,
    __bf16* __restrict__ wt3, __bf16* __restrict__ wt4,
    __bf16* __restrict__ pw1t,
    const float* b1, const float* g1, const float* e1, const float* m1, const float* v1,
    const float* b2, const float* g2, const float* e2, const float* m2, const float* v2,
    const float* b3, const float* g3, const float* e3, const float* m3, const float* v3,
    const float* b4, const float* g4, const float* e4, const float* m4, const float* v4,
    float* __restrict__ bnS, float* __restrict__ bnT,   // [4][256]
    int IN) {
    int b = blockIdx.x;
    if (b >= 928) {
        int l = b - 928;
        int Dl = (l == 3) ? 128 : 256;
        int t = threadIdx.x;
        if (t < Dl) {
            const float* bias; const float* ga; const float* be;
            const float* mu;   const float* va;
            if (l == 0)      { bias = b1; ga = g1; be = e1; mu = m1; va = v1; }
            else if (l == 1) { bias = b2; ga = g2; be = e2; mu = m2; va = v2; }
            else if (l == 2) { bias = b3; ga = g3; be = e3; mu = m3; va = v3; }
            else             { bias = b4; ga = g4; be = e4; mu = m4; va = v4; }
            float S = ga[t] * rsqrtf(va[t] + BN_EPS);
            bnS[l * 256 + t] = S;
            bnT[l * 256 + t] = (bias[t] - mu[t]) * S + be[t];
        }
        return;
    }
    const float* W; __bf16* WT; int K, D, Kpad, col;
    if (b < 256)      { W = W1;  WT = wt1;  K = IN;  D = 256; Kpad = 64;  col = b; }
    else if (b < 512) { W = W2;  WT = wt2;  K = 256; D = 256; Kpad = 256; col = b - 256; }
    else if (b < 768) { W = W3;  WT = wt3;  K = 256; D = 256; Kpad = 256; col = b - 512; }
    else if (b < 896) { W = W4;  WT = wt4;  K = 256; D = 128; Kpad = 256; col = b - 768; }
    else              { W = PW1; WT = pw1t; K = 128; D = 32;  Kpad = 128; col = b - 896; }
    for (int k = threadIdx.x; k < Kpad; k += blockDim.x)
        WT[(size_t)col * Kpad + k] = (k < K) ? (__bf16)W[(size_t)k * D + col] : (__bf16)0.f;
}

// ================= LDS-free MFMA GEMM strip + fused alpha + u8-quant H ====
template<int DCOLS, int HEADS, bool HAS_A2>
__global__ __launch_bounds__(256) void gemm_fused(
    const __bf16* __restrict__ A, const __bf16* __restrict__ A2,
    const __bf16* __restrict__ WT,
    const float* __restrict__ asv, const float* __restrict__ adv,
    uint8_t* __restrict__ H8, float* __restrict__ hscale,
    float* __restrict__ alpha_s, float* __restrict__ alpha_d,
    int M, int K) {
    constexpr int RB = (DCOLS == 256) ? 64 : 128;
    constexpr int NW = (DCOLS == 256) ? 4 : 2;
    const int w    = threadIdx.x >> 6;
    const int lane = threadIdx.x & 63;
    const int l16  = lane & 15, hi4 = lane >> 4;
    const int rg    = (DCOLS == 256) ? 0 : (w >> 1);
    const int ct    = (DCOLS == 256) ? w : (w & 1);
    const int col0w = ct * 64;
    const int rbase = rg * 64;
    const int n0 = blockIdx.x * RB;
    const int lk = hi4 * 8;

    f32x4 acc[4][4] = {};
    int arow[4];
    #pragma unroll
    for (int i = 0; i < 4; ++i) {
        int r = n0 + rbase + i * 16 + l16;
        arow[i] = (r < M) ? r : (M - 1);
    }

    for (int k0 = 0; k0 < K; k0 += 32) {
        bf16x8 af[4], bfr[4];
        #pragma unroll
        for (int i = 0; i < 4; ++i) {
            bf16x8 v = *(const bf16x8*)&A[(size_t)arow[i] * K + k0 + lk];
            if (HAS_A2) {
                bf16x8 v2 = *(const bf16x8*)&A2[(size_t)arow[i] * K + k0 + lk];
                #pragma unroll
                for (int j = 0; j < 8; ++j) v[j] = (__bf16)((float)v[j] + (float)v2[j]);
            }
            af[i] = v;
        }
        #pragma unroll
        for (int j = 0; j < 4; ++j)
            bfr[j] = *(const bf16x8*)&WT[(size_t)(col0w + j * 16 + l16) * K + k0 + lk];
        #pragma unroll
        for (int i = 0; i < 4; ++i)
            #pragma unroll
            for (int j = 0; j < 4; ++j)
                acc[i][j] = __builtin_amdgcn_mfma_f32_16x16x32_bf16(
                    af[i], bfr[j], acc[i][j], 0, 0, 0);
    }

    // ---- fused alpha ----
    float asc[4], adc[4];
    #pragma unroll
    for (int j = 0; j < 4; ++j) {
        int c = col0w + j * 16 + l16;
        asc[j] = asv[c]; adc[j] = adv[c];
    }
    __shared__ float as_l[128][2], ad_l[128][2];
    __shared__ float rmaxl[RB][NW];
    #pragma unroll
    for (int i = 0; i < 4; ++i)
        #pragma unroll
        for (int q = 0; q < 4; ++q) {
            float ps = 0.f, pd = 0.f;
            #pragma unroll
            for (int j = 0; j < 4; ++j) {
                float v = acc[i][j][q];
                ps = fmaf(v, asc[j], ps);
                pd = fmaf(v, adc[j], pd);
            }
            #pragma unroll
            for (int o = 1; o < 16; o <<= 1) {
                ps += __shfl_xor(ps, o, 64);
                pd += __shfl_xor(pd, o, 64);
            }
            int rl = rbase + i * 16 + hi4 * 4 + q;
            if constexpr (DCOLS == 256) {
                int row = n0 + rl;
                if (l16 == 0 && row < M) {
                    alpha_s[row * HEADS + w] = ps;
                    alpha_d[row * HEADS + w] = pd;
                }
            } else {
                if (l16 == 0) { as_l[rl][ct] = ps; ad_l[rl][ct] = pd; }
            }
        }

    // ---- per-row max(|acc|) ----
    float rm[4][4];
    #pragma unroll
    for (int i = 0; i < 4; ++i)
        #pragma unroll
        for (int q = 0; q < 4; ++q) {
            float m = fabsf(acc[i][0][q]);
            #pragma unroll
            for (int j = 1; j < 4; ++j) m = fmaxf(m, fabsf(acc[i][j][q]));
            rm[i][q] = m;
        }
    #pragma unroll
    for (int o = 1; o < 16; o <<= 1)
        #pragma unroll
        for (int i = 0; i < 4; ++i)
            #pragma unroll
            for (int q = 0; q < 4; ++q)
                rm[i][q] = fmaxf(rm[i][q], __shfl_xor(rm[i][q], o, 64));
    if (l16 == 0) {
        #pragma unroll
        for (int i = 0; i < 4; ++i)
            #pragma unroll
            for (int q = 0; q < 4; ++q)
                rmaxl[rbase + i * 16 + hi4 * 4 + q][(DCOLS == 256) ? w : ct] = rm[i][q];
    }
    __syncthreads();

    if constexpr (DCOLS == 128) {
        int t = threadIdx.x;
        if (t < 128) {
            int row = n0 + t;
            if (row < M) {
                alpha_s[row] = as_l[t][0] + as_l[t][1];
                alpha_d[row] = ad_l[t][0] + ad_l[t][1];
            }
        }
    }

    // ---- quantize (excess-128) + store ----
    #pragma unroll
    for (int i = 0; i < 4; ++i)
        #pragma unroll
        for (int q = 0; q < 4; ++q) {
            int rl = rbase + i * 16 + hi4 * 4 + q;
            float m4 = rmaxl[rl][0];
            #pragma unroll
            for (int k = 1; k < NW; ++k) m4 = fmaxf(m4, rmaxl[rl][k]);
            float qinv = (m4 > 1e-30f) ? 127.f / m4 : 0.f;
            int row = n0 + rl;
            if (row < M) {
                if (l16 == 0 && ct == 0 && (DCOLS == 128 || w == 0))
                    hscale[row] = m4 * (1.f / 127.f);
                #pragma unroll
                for (int j = 0; j < 4; ++j)
                    H8[(size_t)row * DCOLS + col0w + j * 16 + l16] =
                        (uint8_t)((int)rintf(acc[i][j][q] * qinv) + 128);
            }
        }
}

// ================= CSR build (once per call) =================
__global__ void deg_count_kernel(const int* __restrict__ ei, int* __restrict__ deg,
                                 int E, int Etot) {
    int e = blockIdx.x * blockDim.x + threadIdx.x;
    if (e >= Etot) return;
    int d = (e < E) ? ei[E + e] : e - E;
    atomicAdd(&deg[d], 1);
}

#define SCB 4096
__global__ __launch_bounds__(256) void scan1_kernel(const int* __restrict__ deg,
                                                    int* __restrict__ bsum, int N) {
    __shared__ int ts[256];
    const int t = threadIdx.x;
    const int base = blockIdx.x * SCB + t * 16;
    int s = 0;
    #pragma unroll
    for (int i = 0; i < 16; ++i) {
        int idx = base + i;
        if (idx < N) s += deg[idx];
    }
    ts[t] = s;
    __syncthreads();
    for (int off = 128; off > 0; off >>= 1) {
        if (t < off) ts[t] += ts[t + off];
        __syncthreads();
    }
    if (t == 0) bsum[blockIdx.x] = ts[0];
}

__global__ __launch_bounds__(256) void scan2_kernel(const int* __restrict__ bsum,
                                                    int* __restrict__ bpref, int B,
                                                    int* __restrict__ rowptrN) {
    __shared__ int sm[256];
    const int t = threadIdx.x;
    int v = (t < B) ? bsum[t] : 0;
    sm[t] = v;
    __syncthreads();
    for (int off = 1; off < 256; off <<= 1) {
        int u = (t >= off) ? sm[t - off] : 0;
        __syncthreads();
        sm[t] += u;
        __syncthreads();
    }
    if (t < B) bpref[t] = sm[t] - v;
    if (t == 255) *rowptrN = sm[255];
}

__global__ __launch_bounds__(256) void scan3_kernel(const int* __restrict__ deg,
                                                    const int* __restrict__ bpref,
                                                    int* __restrict__ rowptr,
                                                    int* __restrict__ cursor, int N) {
    __shared__ int ts[256];
    const int t = threadIdx.x;
    const int base = blockIdx.x * SCB + t * 16;
    int d[16];
    int s = 0;
    #pragma unroll
    for (int i = 0; i < 16; ++i) {
        int idx = base + i;
        d[i] = (idx < N) ? deg[idx] : 0;
        s += d[i];
    }
    ts[t] = s;
    __syncthreads();
    for (int off = 1; off < 256; off <<= 1) {
        int u = (t >= off) ? ts[t - off] : 0;
        __syncthreads();
        ts[t] += u;
        __syncthreads();
    }
    int run = bpref[blockIdx.x] + ts[t] - s;
    #pragma unroll
    for (int i = 0; i < 16; ++i) {
        int idx = base + i;
        if (idx < N) { rowptr[idx] = run; cursor[idx] = run; run += d[i]; }
    }
}

__global__ void scatter_kernel(const int* __restrict__ ei, int* __restrict__ cursor,
                               int* __restrict__ csrc, int E, int Etot) {
    int e = blockIdx.x * blockDim.x + threadIdx.x;
    if (e >= Etot) return;
    int s, d;
    if (e < E) { s = ei[e]; d = ei[E + e]; } else { s = d = e - E; }
    int pos = atomicAdd(&cursor[d], 1);
    csrc[pos] = s;
}

__global__ void gstart_kernel(const int* __restrict__ batch, int* __restrict__ gstart,
                              int N, int G) {
    int n = blockIdx.x * blockDim.x + threadIdx.x;
    if (n >= N) return;
    int b = batch[n];
    if (n == 0) { for (int g = 0; g <= b; ++g) gstart[g] = 0; }
    else {
        int bp = batch[n - 1];
        for (int g = bp + 1; g <= b; ++g) gstart[g] = n;
    }
    if (n == N - 1) { for (int g = b + 1; g <= G; ++g) gstart[g] = N; }
}

// ============ GAT edge phase: TWO nodes per wave (half-wave per node) ============
template<int HEADS, int C>
__global__ __launch_bounds__(256) void gat_agg(
    const int* __restrict__ rowptr, const int* __restrict__ csrc,
    const uint8_t* __restrict__ hf, const float* __restrict__ hscale,
    const float* __restrict__ asrc, const float* __restrict__ adst,
    const float* __restrict__ bnS, const float* __restrict__ bnT,
    __bf16* __restrict__ out, int N) {
    constexpr int D   = HEADS * C;
    constexpr int LPE = D / 8;        // lanes covering one row (32 or 16)
    constexpr int EPH = 32 / LPE;     // edges per half-step (1 or 2)

    const int wid  = threadIdx.x >> 6;
    const int lane = threadIdx.x & 63;
    const int half = lane >> 5;
    const int sl   = lane & 31;

    __shared__ int   soff[4][2][32];
    __shared__ float pal[4][2][32][HEADS];

    const int npairs = (N + 1) >> 1;

    for (int pair = blockIdx.x * 4 + wid; pair < npairs; pair += gridDim.x * 4) {
        const int node = pair * 2 + half;
        const bool valid = node < N;
        const int beg = valid ? rowptr[node] : 0;
        const int end = valid ? rowptr[node + 1] : 0;
        const int deg = end - beg;

        const int grp = (EPH == 1) ? 0 : (sl >> 4);
        const int c0  = (EPH == 1) ? sl * 8 : (sl & 15) * 8;
        const int hd  = c0 / C;
        const uint8_t* hb = hf + c0;

        float ad[HEADS];
        #pragma unroll
        for (int h = 0; h < HEADS; ++h) ad[h] = valid ? adst[node * HEADS + h] : 0.f;

        float acc8[8] = {};
        float psum = 0.f;

        auto fmau8 = [&](uint2 v, float q) {
            acc8[0] = fmaf(ub0(v.x), q, acc8[0]);
            acc8[1] = fmaf(ub1(v.x), q, acc8[1]);
            acc8[2] = fmaf(ub2(v.x), q, acc8[2]);
            acc8[3] = fmaf(ub3(v.x), q, acc8[3]);
            acc8[4] = fmaf(ub0(v.y), q, acc8[4]);
            acc8[5] = fmaf(ub1(v.y), q, acc8[5]);
            acc8[6] = fmaf(ub2(v.y), q, acc8[6]);
            acc8[7] = fmaf(ub3(v.y), q, acc8[7]);
        };

        auto agg_chunk = [&](int cnt) {
            int e = 0;
            for (; e + 4 * EPH <= cnt; e += 4 * EPH) {
                int o0 = soff[wid][half][e + 0 * EPH + grp];
                int o1 = soff[wid][half][e + 1 * EPH + grp];
                int o2 = soff[wid][half][e + 2 * EPH + grp];
                int o3 = soff[wid][half][e + 3 * EPH + grp];
                float q0 = pal[wid][half][e + 0 * EPH + grp][hd];
                float q1 = pal[wid][half][e + 1 * EPH + grp][hd];
                float q2 = pal[wid][half][e + 2 * EPH + grp][hd];
                float q3 = pal[wid][half][e + 3 * EPH + grp][hd];
                uint2 v0 = *(const uint2*)(hb + o0);
                uint2 v1 = *(const uint2*)(hb + o1);
                uint2 v2 = *(const uint2*)(hb + o2);
                uint2 v3 = *(const uint2*)(hb + o3);
                psum += (q0 + q1) + (q2 + q3);
                fmau8(v0, q0); fmau8(v1, q1); fmau8(v2, q2); fmau8(v3, q3);
            }
            for (; e + EPH <= cnt; e += EPH) {
                int o0 = soff[wid][half][e + grp];
                float q0 = pal[wid][half][e + grp][hd];
                uint2 v0 = *(const uint2*)(hb + o0);
                psum += q0;
                fmau8(v0, q0);
            }
            if (EPH == 2 && e < cnt) {      // odd tail: only grp 0 real
                int r = cnt - e;            // ==1
                int idx = (grp < r) ? e + grp : e;     // clamped, never negative
                int o0 = soff[wid][half][idx];
                float q0 = (grp < r) ? pal[wid][half][idx][hd] : 0.f;
                uint2 v0 = *(const uint2*)(hb + o0);
                psum += q0;
                fmau8(v0, q0);
            }
        };

        if (deg <= 32) {
            // ---- fast path: slot sl = edge, width-32 butterflies ----
            const bool act = sl < deg;
            int msrc = act ? csrc[beg + sl] : 0;
            float hs = act ? hscale[msrc] : 0.f;
            float lv[HEADS];
            if constexpr (HEADS == 4) {
                float4 a4 = ((const float4*)asrc)[msrc];
                lv[0] = a4.x; lv[1] = a4.y; lv[2] = a4.z; lv[3] = a4.w;
            } else {
                lv[0] = asrc[msrc];
            }
            float p[HEADS];
            #pragma unroll
            for (int h = 0; h < HEADS; ++h) {
                float v;
                if (act) { v = lv[h] + ad[h]; v = v > 0.f ? v : NEG_SLOPE * v; }
                else v = -INFINITY;
                float mx = v;
                #pragma unroll
                for (int o = 1; o < 32; o <<= 1) mx = fmaxf(mx, __shfl_xor(mx, o, 64));
                float pe = act ? __expf(v - mx) : 0.f;
                float ps = pe;
                #pragma unroll
                for (int o = 1; o < 32; o <<= 1) ps += __shfl_xor(ps, o, 64);
                p[h] = pe * (1.f / (ps + 1e-16f)) * hs;
            }
            soff[wid][half][sl] = msrc * D;
            if constexpr (HEADS == 4)
                *(float4*)&pal[wid][half][sl][0] = make_float4(p[0], p[1], p[2], p[3]);
            else
                pal[wid][half][sl][0] = p[0];
            asm volatile("s_waitcnt lgkmcnt(0)" ::: "memory");
            agg_chunk(deg);
        } else {
            // ---- general path (deg > 32; rare), per-half strided two-pass ----
            float mx[HEADS], sm[HEADS], inv[HEADS];
            #pragma unroll
            for (int h = 0; h < HEADS; ++h) mx[h] = -INFINITY;
            for (int j = beg + sl; j < end; j += 32) {
                int s = csrc[j];
                #pragma unroll
                for (int h = 0; h < HEADS; ++h) {
                    float v = asrc[s * HEADS + h] + ad[h];
                    v = v > 0.f ? v : NEG_SLOPE * v;
                    mx[h] = fmaxf(mx[h], v);
                }
            }
            #pragma unroll
            for (int h = 0; h < HEADS; ++h) {
                #pragma unroll
                for (int o = 1; o < 32; o <<= 1) mx[h] = fmaxf(mx[h], __shfl_xor(mx[h], o, 64));
                sm[h] = 0.f;
            }
            for (int j = beg + sl; j < end; j += 32) {
                int s = csrc[j];
                #pragma unroll
                for (int h = 0; h < HEADS; ++h) {
                    float v = asrc[s * HEADS + h] + ad[h];
                    v = v > 0.f ? v : NEG_SLOPE * v;
                    sm[h] += __expf(v - mx[h]);
                }
            }
            #pragma unroll
            for (int h = 0; h < HEADS; ++h) {
                #pragma unroll
                for (int o = 1; o < 32; o <<= 1) sm[h] += __shfl_xor(sm[h], o, 64);
                inv[h] = 1.f / (sm[h] + 1e-16f);
            }
            for (int base2 = beg; base2 < end; base2 += 32) {
                int ne = min(32, end - base2);
                bool act2 = sl < ne;
                int msrc = csrc[base2 + (act2 ? sl : 0)];
                float hs = act2 ? hscale[msrc] : 0.f;
                soff[wid][half][sl] = msrc * D;
                #pragma unroll
                for (int h = 0; h < HEADS; ++h) {
                    float pv = 0.f;
                    if (act2) {
                        float v = asrc[msrc * HEADS + h] + ad[h];
                        v = v > 0.f ? v : NEG_SLOPE * v;
                        pv = __expf(v - mx[h]) * inv[h] * hs;
                    }
                    pal[wid][half][sl][h] = pv;
                }
                asm volatile("s_waitcnt lgkmcnt(0)" ::: "memory");
                agg_chunk(ne);
                asm volatile("s_waitcnt lgkmcnt(0)" ::: "memory");
            }
        }

        // ---- merge (D=128 only: lanes sl, sl^16 share cols) ----
        if constexpr (EPH == 2) {
            #pragma unroll
            for (int i = 0; i < 8; ++i)
                acc8[i] += __shfl_xor(acc8[i], 16, 64);
            psum += __shfl_xor(psum, 16, 64);
        }

        // ---- epilogue: excess-128 fix + folded BN + ReLU -> bf16 ----
        if (valid && (EPH == 1 || sl < 16)) {
            float4 Sa = *(const float4*)&bnS[c0];
            float4 Sb = *(const float4*)&bnS[c0 + 4];
            float4 Ta = *(const float4*)&bnT[c0];
            float4 Tb = *(const float4*)&bnT[c0 + 4];
            float S8[8] = {Sa.x, Sa.y, Sa.z, Sa.w, Sb.x, Sb.y, Sb.z, Sb.w};
            float T8[8] = {Ta.x, Ta.y, Ta.z, Ta.w, Tb.x, Tb.y, Tb.z, Tb.w};
            bf16x8 ov;
            #pragma unroll
            for (int i = 0; i < 8; ++i) {
                float v = fmaf(acc8[i] - 128.f * psum, S8[i], T8[i]);
                ov[i] = (__bf16)fmaxf(v, 0.f);
            }
            *(bf16x8*)&out[(size_t)node * D + c0] = ov;
        }
    }
}

// ---------- gate MLP via MFMA ----------
__global__ __launch_bounds__(256) void gate_gemm_kernel(
    const __bf16* __restrict__ x4, const __bf16* __restrict__ pw1t,
    const float* __restrict__ pb1, const float* __restrict__ pw2,
    const float* __restrict__ pb2, float* __restrict__ gate, int N) {
    const int w    = threadIdx.x >> 6;
    const int lane = threadIdx.x & 63;
    const int l16  = lane & 15, hi4 = lane >> 4;
    const int n0 = (blockIdx.x * 4 + w) * 16;
    if (n0 >= N) return;
    const int arow = min(n0 + l16, N - 1);
    f32x4 acc[2] = {};
    #pragma unroll
    for (int k0 = 0; k0 < 128; k0 += 32) {
        bf16x8 af = *(const bf16x8*)&x4[(size_t)arow * 128 + k0 + hi4 * 8];
        bf16x8 b0 = *(const bf16x8*)&pw1t[(size_t)l16 * 128 + k0 + hi4 * 8];
        bf16x8 b1 = *(const bf16x8*)&pw1t[(size_t)(16 + l16) * 128 + k0 + hi4 * 8];
        acc[0] = __builtin_amdgcn_mfma_f32_16x16x32_bf16(af, b0, acc[0], 0, 0, 0);
        acc[1] = __builtin_amdgcn_mfma_f32_16x16x32_bf16(af, b1, acc[1], 0, 0, 0);
    }
    float pb1a = pb1[l16], pb1b = pb1[16 + l16];
    float w2a = pw2[l16], w2b = pw2[16 + l16];
    #pragma unroll
    for (int q = 0; q < 4; ++q) {
        float g = fmaxf(acc[0][q] + pb1a, 0.f) * w2a +
                  fmaxf(acc[1][q] + pb1b, 0.f) * w2b;
        #pragma unroll
        for (int o = 1; o < 16; o <<= 1) g += __shfl_xor(g, o, 64);
        int row = n0 + hi4 * 4 + q;
        if (l16 == 0 && row < N) gate[row] = g + pb2[0];
    }
}

// ---------- block-per-graph pooling ----------
__global__ __launch_bounds__(128) void pool_kernel(
    const __bf16* __restrict__ x4, const float* __restrict__ gate,
    const int* __restrict__ gstart, float* __restrict__ out) {
    const int g = blockIdx.x;
    const int t = threadIdx.x;
    const int beg = gstart[g], end = gstart[g + 1];
    __shared__ float red[128];
    __shared__ float wbuf[128];
    float m = -INFINITY;
    for (int n = beg + t; n < end; n += 128) m = fmaxf(m, gate[n]);
    red[t] = m; __syncthreads();
    for (int off = 64; off > 0; off >>= 1) {
        if (t < off) red[t] = fmaxf(red[t], red[t + off]);
        __syncthreads();
    }
    m = red[0]; __syncthreads();
    float s = 0.f;
    for (int n = beg + t; n < end; n += 128) s += expf(gate[n] - m);
    red[t] = s; __syncthreads();
    for (int off = 64; off > 0; off >>= 1) {
        if (t < off) red[t] += red[t + off];
        __syncthreads();
    }
    const float inv = 1.f / (red[0] + 1e-16f);
    __syncthreads();
    float acc = 0.f;
    for (int base = beg; base < end; base += 128) {
        int ne = min(128, end - base);
        if (t < ne) wbuf[t] = expf(gate[base + t] - m) * inv;
        __syncthreads();
        for (int i = 0; i < ne; ++i)
            acc = fmaf(wbuf[i], (float)x4[(size_t)(base + i) * 128 + t], acc);
        __syncthreads();
    }
    out[(size_t)g * 160 + t] = acc;
}

// ---------- global-feature MLP ----------
__global__ void gfeat_kernel(const float* __restrict__ gfeat,
                             const float* __restrict__ gw, const float* __restrict__ gb,
                             float* __restrict__ out) {
    const int g = blockIdx.x;
    const int k = threadIdx.x;
    if (k < 32) {
        float t = gb[k];
        #pragma unroll
        for (int j = 0; j < 7; ++j) t = fmaf(gfeat[g * 7 + j], gw[j * 32 + k], t);
        out[(size_t)g * 160 + 128 + k] = fmaxf(t, 0.f);
    }
}

// ==========================================================================
extern "C" void kernel_launch(void* const* d_in, const int* in_sizes, int n_in,
                              void* d_out, int out_size, void* d_ws, size_t ws_size,
                              hipStream_t stream) {
    const float* x      = (const float*)d_in[0];
    const int*   ei     = (const int*)  d_in[1];
    const int*   batch  = (const int*)  d_in[2];
    const float* gfeat  = (const float*)d_in[3];

    const int N    = in_sizes[2];
    const int E    = in_sizes[1] / 2;
    const int G    = in_sizes[3] / 7;
    const int IN   = in_sizes[0] / N;
    const int Etot = E + N;
    const int INp  = 64;

    const float* W[4];  const float* avs[4]; const float* avd[4]; const float* bi[4];
    const float* ga[4]; const float* be[4];  const float* mu[4];  const float* va[4];
    for (int l = 0; l < 4; ++l) {
        int o = 4 + 8 * l;
        W[l]   = (const float*)d_in[o + 0];
        avs[l] = (const float*)d_in[o + 1];
        avd[l] = (const float*)d_in[o + 2];
        bi[l]  = (const float*)d_in[o + 3];
        ga[l]  = (const float*)d_in[o + 4];
        be[l]  = (const float*)d_in[o + 5];
        mu[l]  = (const float*)d_in[o + 6];
        va[l]  = (const float*)d_in[o + 7];
    }
    const float* pw1 = (const float*)d_in[36];
    const float* pb1 = (const float*)d_in[37];
    const float* pw2 = (const float*)d_in[38];
    const float* pb2 = (const float*)d_in[39];
    const float* gw  = (const float*)d_in[40];
    const float* gb  = (const float*)d_in[41];

    float* out = (float*)d_out;

    float* ws = (float*)d_ws;
    __bf16* xb = (__bf16*)ws; ws += (size_t)N * 32;
    uint8_t* h8 = (uint8_t*)ws; ws += (size_t)N * 64;
    float* hsc = ws;  ws += N;
    __bf16* x1 = (__bf16*)ws; ws += (size_t)N * 128;
    __bf16* x2 = (__bf16*)ws; ws += (size_t)N * 128;
    __bf16* x3 = (__bf16*)ws; ws += (size_t)N * 128;
    __bf16* wt1 = (__bf16*)ws; ws += 256 * 64 / 2;
    __bf16* wt2 = (__bf16*)ws; ws += 256 * 256 / 2;
    __bf16* wt3 = (__bf16*)ws; ws += 256 * 256 / 2;
    __bf16* wt4 = (__bf16*)ws; ws += 128 * 256 / 2;
    __bf16* pw1t = (__bf16*)ws; ws += 32 * 128 / 2;
    float* bnS = ws; ws += 4 * 256;
    float* bnT = ws; ws += 4 * 256;
    float* asrc = ws;  ws += (size_t)N * 4;
    float* adst = ws;  ws += (size_t)N * 4;
    float* gate = ws;  ws += N;
    int* deg    = (int*)ws; ws += N;
    int* cursor = (int*)ws; ws += N;
    int* rowptr = (int*)ws; ws += (N + 1);
    int* csrc   = (int*)ws; ws += Etot;
    int* gstart = (int*)ws; ws += (G + 1);
    int* bsum   = (int*)ws; ws += 256;
    int* bpref  = (int*)ws; ws += 256;
    __bf16* x4 = x1;

    const int SB = (N + SCB - 1) / SCB;

    hipLaunchKernelGGL(conv_pad_kernel, dim3(512), dim3(256), 0, stream, x, xb, N, IN, INp);
    hipLaunchKernelGGL(prep_all_kernel, dim3(932), dim3(256), 0, stream,
                       W[0], W[1], W[2], W[3], pw1, wt1, wt2, wt3, wt4, pw1t,
                       bi[0], ga[0], be[0], mu[0], va[0],
                       bi[1], ga[1], be[1], mu[1], va[1],
                       bi[2], ga[2], be[2], mu[2], va[2],
                       bi[3], ga[3], be[3], mu[3], va[3],
                       bnS, bnT, IN);

    hipMemsetAsync(deg, 0, (size_t)N * 4, stream);
    hipLaunchKernelGGL(deg_count_kernel, dim3((Etot + 255) / 256), dim3(256), 0, stream,
                       ei, deg, E, Etot);
    hipLaunchKernelGGL(scan1_kernel, dim3(SB), dim3(256), 0, stream, deg, bsum, N);
    hipLaunchKernelGGL(scan2_kernel, dim3(1), dim3(256), 0, stream, bsum, bpref, SB,
                       &rowptr[N]);
    hipLaunchKernelGGL(scan3_kernel, dim3(SB), dim3(256), 0, stream, deg, bpref,
                       rowptr, cursor, N);
    hipLaunchKernelGGL(scatter_kernel, dim3((Etot + 255) / 256), dim3(256), 0, stream,
                       ei, cursor, csrc, E, Etot);
    hipLaunchKernelGGL(gstart_kernel, dim3((N + 255) / 256), dim3(256), 0, stream,
                       batch, gstart, N, G);

    const int grid256 = (N + 63) / 64;
    const int grid128 = (N + 127) / 128;
    const int gatgrid = 2048;   // 8 waves/SIMD; grid-stride over node pairs

    hipLaunchKernelGGL((gemm_fused<256, 4, false>), dim3(grid256), dim3(256), 0, stream,
                       xb, nullptr, wt1, avs[0], avd[0], h8, hsc, asrc, adst, N, INp);
    hipLaunchKernelGGL((gat_agg<4, 64>), dim3(gatgrid), dim3(256), 0, stream,
                       rowptr, csrc, h8, hsc, asrc, adst, bnS + 0, bnT + 0, x1, N);
    hipLaunchKernelGGL((gemm_fused<256, 4, false>), dim3(grid256), dim3(256), 0, stream,
                       x1, nullptr, wt2, avs[1], avd[1], h8, hsc, asrc, adst, N, 256);
    hipLaunchKernelGGL((gat_agg<4, 64>), dim3(gatgrid), dim3(256), 0, stream,
                       rowptr, csrc, h8, hsc, asrc, adst, bnS + 256, bnT + 256, x2, N);
    hipLaunchKernelGGL((gemm_fused<256, 4, true>), dim3(grid256), dim3(256), 0, stream,
                       x1, x2, wt3, avs[2], avd[2], h8, hsc, asrc, adst, N, 256);
    hipLaunchKernelGGL((gat_agg<4, 64>), dim3(gatgrid), dim3(256), 0, stream,
                       rowptr, csrc, h8, hsc, asrc, adst, bnS + 512, bnT + 512, x3, N);
    hipLaunchKernelGGL((gemm_fused<128, 1, false>), dim3(grid128), dim3(256), 0, stream,
                       x3, nullptr, wt4, avs[3], avd[3], h8, hsc, asrc, adst, N, 256);
    hipLaunchKernelGGL((gat_agg<1, 128>), dim3(gatgrid), dim3(256), 0, stream,
                       rowptr, csrc, h8, hsc, asrc, adst, bnS + 768, bnT + 768, x4, N);

    hipLaunchKernelGGL(gate_gemm_kernel, dim3((N + 63) / 64), dim3(256), 0, stream,
                       x4, pw1t, pb1, pw2, pb2, gate, N);
    hipLaunchKernelGGL(pool_kernel, dim3(G), dim3(128), 0, stream, x4, gate, gstart, out);
    hipLaunchKernelGGL(gfeat_kernel, dim3(G), dim3(64), 0, stream, gfeat, gw, gb, out);
}